// Round 5
// baseline (356.026 us; speedup 1.0000x reference)
//
#include <hip/hip_runtime.h>
#include <hip/hip_bf16.h>

#define D 45
#define LSEQ 4096
#define NB 8
#define U 45
#define FH 128
#define KP 48          // padded K row (floats), 192 B
#define SPLIT 16       // s-range slices for qkmax
constexpr float LN_EPS = 1e-12f;

// ---------------------------------------------------------------------------
// Kernel 1:
//   z=0: Xt[b][d][l] = x[b][l][d]              (d-major, for coalesced q loads)
//   z=1: Ksm[b][s][0..47] = gathered K row     (s-major, 192B padded rows)
// ---------------------------------------------------------------------------
__global__ void transpose_kernel(const float* __restrict__ x, const int* __restrict__ idx,
                                 float* __restrict__ Xt, float* __restrict__ Ksm) {
  const int b = blockIdx.y;
  const int z = blockIdx.z;
  const int r0 = blockIdx.x * 64;
  const float* xb = x + (size_t)b * LSEQ * D;
  if (z == 0) {
    __shared__ float tile[D][65];
    for (int i = threadIdx.x; i < 64 * D; i += 256) {
      int j = i / D, d = i - j * D;
      tile[d][j] = xb[(size_t)(r0 + j) * D + d];
    }
    __syncthreads();
    float* dst = Xt + (size_t)b * D * LSEQ + r0;
    for (int i = threadIdx.x; i < D * 64; i += 256) {
      int d = i >> 6, j = i & 63;
      dst[(size_t)d * LSEQ + j] = tile[d][j];
    }
  } else {
    float* kb = Ksm + ((size_t)b * LSEQ + r0) * KP;
    for (int i = threadIdx.x; i < 64 * KP; i += 256) {
      int j = i / KP, d = i - j * KP;
      int row = idx[r0 + j];
      kb[i] = (d < D) ? xb[(size_t)row * D + d] : 0.0f;
    }
  }
}

// ---------------------------------------------------------------------------
// Kernel 2: Ksum[b][d] = sum_s Ksm[b][s][d]   (deterministic, no atomics)
// ---------------------------------------------------------------------------
__global__ void ksum_kernel(const float* __restrict__ Ksm, float* __restrict__ Ksum) {
  __shared__ float sAcc[256][D + 1];
  const int b = blockIdx.x;
  const int tid = threadIdx.x;
  float acc[D];
#pragma unroll
  for (int d = 0; d < D; ++d) acc[d] = 0.f;
  const float* kb = Ksm + (size_t)b * LSEQ * KP;
  for (int s = tid; s < LSEQ; s += 256) {
    const float* kr = kb + (size_t)s * KP;
#pragma unroll
    for (int d = 0; d < D; ++d) acc[d] += kr[d];
  }
#pragma unroll
  for (int d = 0; d < D; ++d) sAcc[tid][d] = acc[d];
  __syncthreads();
  for (int st = 128; st >= 1; st >>= 1) {
    if (tid < st)
      for (int d = 0; d < D; ++d) sAcc[tid][d] += sAcc[tid + st][d];
    __syncthreads();
  }
  if (tid < D) Ksum[b * D + tid] = sAcc[0][tid];
}

// ---------------------------------------------------------------------------
// Kernel 3 (HOT): Mpart[sc][b][l] = max over 256-key slice of dot(q_l, k_s).
// Q in registers (2 rows/lane). K staged in LDS (128-key tiles), read with
// wave-uniform addresses -> hardware broadcast, zero bank conflicts, and the
// reads pipeline in VGPRs (unlike round-4's serial s_load path).
// Each block owns a distinct key-slice -> direct Mpart store, no reduction.
// ---------------------------------------------------------------------------
__global__ __launch_bounds__(256, 3) void qkmax_kernel(const float* __restrict__ Xt,
                                                       const float* __restrict__ Ksm,
                                                       float* __restrict__ Mpart) {
  __shared__ float Ks[128 * KP];  // 24576 B
  const int b = blockIdx.y;
  const int sc = blockIdx.z;
  const int l0 = blockIdx.x * 512;
  const int tid = threadIdx.x;

  // q rows in registers: this thread owns rows l0+tid and l0+256+tid
  float q0[D], q1[D];
  const float* XtB = Xt + (size_t)b * D * LSEQ;
#pragma unroll
  for (int d = 0; d < D; ++d) {
    q0[d] = XtB[(size_t)d * LSEQ + l0 + tid];
    q1[d] = XtB[(size_t)d * LSEQ + l0 + 256 + tid];
  }

  const float* kbase = Ksm + ((size_t)b * LSEQ + sc * 256) * KP;
  float m0 = -INFINITY, m1 = -INFINITY;

  for (int t = 0; t < 2; ++t) {  // two 128-key tiles
    __syncthreads();
    {  // stage tile: 128*48 floats = 1536 float4, coalesced
      const float4* src = reinterpret_cast<const float4*>(kbase + (size_t)t * 128 * KP);
      float4* dst = reinterpret_cast<float4*>(Ks);
      for (int i = tid; i < 1536; i += 256) dst[i] = src[i];
    }
    __syncthreads();

    for (int s = 0; s < 128; ++s) {
      const float* kr = Ks + s * KP;  // wave-uniform -> broadcast ds_read
      float a0 = 0.f, a1 = 0.f, c0 = 0.f, c1 = 0.f;
#pragma unroll
      for (int ch = 0; ch < 11; ++ch) {
        const float4 kv = *reinterpret_cast<const float4*>(kr + ch * 4);
        float& A = (ch & 1) ? a1 : a0;
        float& C = (ch & 1) ? c1 : c0;
        A = fmaf(q0[ch * 4 + 0], kv.x, A); C = fmaf(q1[ch * 4 + 0], kv.x, C);
        A = fmaf(q0[ch * 4 + 1], kv.y, A); C = fmaf(q1[ch * 4 + 1], kv.y, C);
        A = fmaf(q0[ch * 4 + 2], kv.z, A); C = fmaf(q1[ch * 4 + 2], kv.z, C);
        A = fmaf(q0[ch * 4 + 3], kv.w, A); C = fmaf(q1[ch * 4 + 3], kv.w, C);
      }
      const float k44 = kr[44];
      a0 = fmaf(q0[44], k44, a0);
      c0 = fmaf(q1[44], k44, c0);
      m0 = fmaxf(m0, a0 + a1);
      m1 = fmaxf(m1, c0 + c1);
    }
  }

  Mpart[((size_t)sc * NB + b) * LSEQ + l0 + tid] = m0;
  Mpart[((size_t)sc * NB + b) * LSEQ + l0 + 256 + tid] = m1;
}

// ---------------------------------------------------------------------------
// Kernel 4: M = max_sc(Mpart) - dot(q, Ksum)/L ; exact top-45 via 8-bit MSB
// radix-select. Tie semantics identical to jax.lax.top_k (value desc, index
// asc). Also gathers the selected Q rows into Qg[b][u][d].
// ---------------------------------------------------------------------------
__global__ __launch_bounds__(256) void topk_kernel(const float* __restrict__ x,
                                                   const float* __restrict__ Xt,
                                                   const float* __restrict__ Ksum,
                                                   const float* __restrict__ Mpart,
                                                   float* __restrict__ Qg) {
  __shared__ float ks[D];
  __shared__ int hist[256];
  __shared__ int wsum[4];
  __shared__ int bin_s, need_s, cntG_s, cntEq_s, minv_s;
  __shared__ unsigned long long cand[U];
  __shared__ int eqIdx[LSEQ];
  __shared__ int sel[U];
  const int b = blockIdx.x;
  const int tid = threadIdx.x;
  const int lane = tid & 63, wv = tid >> 6;

  if (tid < D) ks[tid] = Ksum[b * D + tid];
  __syncthreads();

  // 1. compute keys (monotonic map of M values), kept in registers
  uint32_t kreg[16];
  const float* XtB = Xt + (size_t)b * D * LSEQ;
#pragma unroll
  for (int k2 = 0; k2 < 16; ++k2) {
    const int l = tid + (k2 << 8);
    float mx = -INFINITY;
#pragma unroll
    for (int p = 0; p < SPLIT; ++p)
      mx = fmaxf(mx, Mpart[((size_t)p * NB + b) * LSEQ + l]);
    float dot = 0.f;
    for (int d = 0; d < D; ++d) dot = fmaf(XtB[(size_t)d * LSEQ + l], ks[d], dot);
    const float v = mx - dot * (1.0f / LSEQ);
    uint32_t u = __float_as_uint(v);
    u ^= (u & 0x80000000u) ? 0xFFFFFFFFu : 0x80000000u;
    kreg[k2] = u;
  }

  // 2. radix select: find exact 45th-largest key T and need (# of T-dups kept)
  const uint32_t pmaskA[4] = {0u, 0xFF000000u, 0xFFFF0000u, 0xFFFFFF00u};
  uint32_t P = 0;
  int need = U;
#pragma unroll
  for (int r = 0; r < 4; ++r) {
    const int shift = 24 - 8 * r;
    hist[tid] = 0;
    __syncthreads();
#pragma unroll
    for (int k2 = 0; k2 < 16; ++k2) {
      const uint32_t key = kreg[k2];
      if (((key ^ P) & pmaskA[r]) == 0) atomicAdd(&hist[(key >> shift) & 0xFF], 1);
    }
    __syncthreads();
    const int h = hist[255 - tid];
    int s = h;
#pragma unroll
    for (int off = 1; off < 64; off <<= 1) {
      int t2 = __shfl_up(s, off);
      if (lane >= off) s += t2;
    }
    if (lane == 63) wsum[wv] = s;
    __syncthreads();
    for (int w2 = 0; w2 < wv; ++w2) s += wsum[w2];
    const int above = s - h;
    if (above < need && s >= need) { bin_s = 255 - tid; need_s = need - above; }
    __syncthreads();
    P |= ((uint32_t)bin_s) << shift;
    need = need_s;
    __syncthreads();
  }
  const uint32_t T = P;

  // 3. collect strictly-greater keys + equal-key indices
  if (tid == 0) { cntG_s = 0; cntEq_s = 0; }
  __syncthreads();
#pragma unroll
  for (int k2 = 0; k2 < 16; ++k2) {
    const uint32_t key = kreg[k2];
    const int l = tid + (k2 << 8);
    if (key > T) {
      int p = atomicAdd(&cntG_s, 1);
      cand[p] = ((unsigned long long)key << 32) | (unsigned long long)(4095 - l);
    } else if (key == T) {
      int p = atomicAdd(&cntEq_s, 1);
      eqIdx[p] = l;
    }
  }
  __syncthreads();
  const int G = cntG_s;
  const int nEq = cntEq_s;
  for (int j = 0; j < need; ++j) {
    int mv2 = 0x7FFFFFFF;
    for (int i = tid; i < nEq; i += 256) mv2 = min(mv2, eqIdx[i]);
#pragma unroll
    for (int off = 32; off; off >>= 1) mv2 = min(mv2, __shfl_xor(mv2, off));
    if (lane == 0) wsum[wv] = mv2;
    __syncthreads();
    if (tid == 0) {
      int m2 = min(min(wsum[0], wsum[1]), min(wsum[2], wsum[3]));
      cand[G + j] = ((unsigned long long)T << 32) | (unsigned long long)(4095 - m2);
      minv_s = m2;
    }
    __syncthreads();
    for (int i = tid; i < nEq; i += 256)
      if (eqIdx[i] == minv_s) eqIdx[i] = 0x7FFFFFFF;
    __syncthreads();
  }

  // 4. rank sort (value desc, index asc) — packed keys are unique
  if (tid < U) {
    const unsigned long long cu = cand[tid];
    int rank = 0;
    for (int v2 = 0; v2 < U; ++v2) rank += (cand[v2] > cu);
    sel[rank] = 4095 - (int)(cu & 0xFFFFFFFFull);
  }
  __syncthreads();

  // 5. gather selected Q rows
  const float* xb = x + (size_t)b * LSEQ * D;
  for (int i = tid; i < U * D; i += 256) {
    int u2 = i / D, d = i - u2 * D;
    Qg[(size_t)b * U * D + i] = xb[(size_t)sel[u2] * D + d];
  }
}

// ---------------------------------------------------------------------------
// Kernel 5: sparse attention, chunked-parallel (unchanged).
// ---------------------------------------------------------------------------
__global__ void attn_pv_kernel(const float* __restrict__ x, const float* __restrict__ Qg,
                               float* __restrict__ PVpart) {
  __shared__ float Xs[256][D + 2];
  __shared__ float eS[256][U + 1];
  const int chunk = blockIdx.x, b = blockIdx.y;
  const int tid = threadIdx.x;
  const int l0 = chunk * 256;
  const float* xb = x + ((size_t)b * LSEQ + l0) * D;
  for (int i = tid; i < 256 * D; i += 256) {
    int l = i / D, d = i - l * D;
    Xs[l][d] = xb[i];
  }
  Xs[tid][D] = 1.0f;
  __syncthreads();

  float xr[D];
#pragma unroll
  for (int d = 0; d < D; ++d) xr[d] = Xs[tid][d];
  const float scale = 0.14907119849998599f;  // 1/sqrt(45)
  const float* qb = Qg + (size_t)b * U * D;
  for (int u = 0; u < U; ++u) {
    float acc = 0.f;
#pragma unroll
    for (int d = 0; d < D; ++d) acc = fmaf(qb[u * D + d], xr[d], acc);
    eS[tid][u] = __expf(acc * scale);
  }
  __syncthreads();

  float* outp = PVpart + (size_t)(b * 16 + chunk) * (U * (D + 1));
  for (int idx = tid; idx < U * (D + 1); idx += 256) {
    int u = idx / (D + 1), c = idx - u * (D + 1);
    float acc = 0.f;
#pragma unroll 4
    for (int l = 0; l < 256; ++l) acc = fmaf(eS[l][u], Xs[l][c], acc);
    outp[idx] = acc;
  }
}

// ---------------------------------------------------------------------------
// Kernel 6: combine PV partials -> LN1 -> FFN -> LN2 -> out (unchanged).
// ---------------------------------------------------------------------------
__global__ void epilogue_kernel(const float* __restrict__ PVpart,
                                const float* __restrict__ W1, const float* __restrict__ b1,
                                const float* __restrict__ W2, const float* __restrict__ b2,
                                const float* __restrict__ g1, const float* __restrict__ be1,
                                const float* __restrict__ g2, const float* __restrict__ be2,
                                float* __restrict__ out) {
  __shared__ float hA[D][46];
  __shared__ float den[U];
  __shared__ float Wbuf[FH * D];
  __shared__ float f1s[D][FH + 1];
  __shared__ float f2T[D][46];
  const int b = blockIdx.x;
  const int tid = threadIdx.x;
  const float* PV = PVpart + (size_t)b * 16 * U * (D + 1);
  if (tid < U) {
    float s = 0.f;
    for (int c = 0; c < 16; ++c) s += PV[(size_t)c * U * (D + 1) + tid * (D + 1) + D];
    den[tid] = 1.0f / s;
  }
  for (int i = tid; i < FH * D; i += 256) Wbuf[i] = W1[i];
  __syncthreads();
  for (int i = tid; i < U * D; i += 256) {
    int u = i / D, d = i - u * D;
    float s = 0.f;
    for (int c = 0; c < 16; ++c) s += PV[(size_t)c * U * (D + 1) + u * (D + 1) + d];
    hA[u][d] = s * den[u];
  }
  __syncthreads();
  if (tid < U) {
    const int u = tid;
    float mean = 0.f;
    for (int d = 0; d < D; ++d) mean += hA[u][d];
    mean *= (1.0f / D);
    float var = 0.f;
    for (int d = 0; d < D; ++d) { float t = hA[u][d] - mean; var += t * t; }
    var *= (1.0f / D);
    const float inv = 1.0f / sqrtf(var + LN_EPS);
    for (int d = 0; d < D; ++d) hA[u][d] = g1[d] * ((hA[u][d] - mean) * inv) + be1[d];
  }
  __syncthreads();
  for (int i = tid; i < D * FH; i += 256) {
    const int d = i >> 7, hh = i & 127;
    float acc = b1[hh];
    for (int uu = 0; uu < U; ++uu) acc = fmaf(hA[uu][d], Wbuf[hh * D + uu], acc);
    f1s[d][hh] = fmaxf(acc, 0.f);
  }
  __syncthreads();
  for (int i = tid; i < U * FH; i += 256) Wbuf[i] = W2[i];
  __syncthreads();
  for (int i = tid; i < U * D; i += 256) {
    const int u = i / D, d = i - u * D;
    float acc = b2[u];
    for (int h = 0; h < FH; ++h) acc = fmaf(f1s[d][h], Wbuf[u * FH + h], acc);
    f2T[u][d] = acc;
  }
  __syncthreads();
  if (tid < U) {
    const int u = tid;
    float mean = 0.f;
    for (int d = 0; d < D; ++d) mean += f2T[u][d];
    mean *= (1.0f / D);
    float var = 0.f;
    for (int d = 0; d < D; ++d) { float t = f2T[u][d] - mean; var += t * t; }
    var *= (1.0f / D);
    const float inv = 1.0f / sqrtf(var + LN_EPS);
    float* ob = out + ((size_t)b * U + u) * D;
    for (int d = 0; d < D; ++d) ob[d] = g2[d] * ((f2T[u][d] - mean) * inv) + be2[d];
  }
}

// ---------------------------------------------------------------------------
extern "C" void kernel_launch(void* const* d_in, const int* in_sizes, int n_in,
                              void* d_out, int out_size, void* d_ws, size_t ws_size,
                              hipStream_t stream) {
  const float* x = (const float*)d_in[0];
  const float* W1 = (const float*)d_in[1];
  const float* b1 = (const float*)d_in[2];
  const float* W2 = (const float*)d_in[3];
  const float* b2 = (const float*)d_in[4];
  const float* g1 = (const float*)d_in[5];
  const float* be1 = (const float*)d_in[6];
  const float* g2 = (const float*)d_in[7];
  const float* be2 = (const float*)d_in[8];
  const int* idx = (const int*)d_in[9];
  float* out = (float*)d_out;

  // ws layout (floats): Xt | Ksm | Ksum | Mpart | Qg | PVpart  (~14.5 MiB)
  char* w = (char*)d_ws;
  float* Xt = (float*)w;
  float* Ksm = Xt + (size_t)NB * D * LSEQ;
  float* Ksum = Ksm + (size_t)NB * LSEQ * KP;
  float* Mpart = Ksum + 1024;
  float* Qg = Mpart + (size_t)SPLIT * NB * LSEQ;
  float* PVpart = Qg + (size_t)NB * U * D + 64;

  transpose_kernel<<<dim3(LSEQ / 64, NB, 2), 256, 0, stream>>>(x, idx, Xt, Ksm);
  ksum_kernel<<<dim3(NB), 256, 0, stream>>>(Ksm, Ksum);
  qkmax_kernel<<<dim3(LSEQ / 512, NB, SPLIT), 256, 0, stream>>>(Xt, Ksm, Mpart);
  topk_kernel<<<dim3(NB), 256, 0, stream>>>(x, Xt, Ksum, Mpart, Qg);
  attn_pv_kernel<<<dim3(16, NB), 256, 0, stream>>>(x, Qg, PVpart);
  epilogue_kernel<<<dim3(NB), 256, 0, stream>>>(PVpart, W1, b1, W2, b2, g1, be1, g2, be2, out);
}

// Round 6
// 235.156 us; speedup vs baseline: 1.5140x; 1.5140x over previous
//
#include <hip/hip_runtime.h>
#include <hip/hip_bf16.h>

#define D 45
#define LSEQ 4096
#define NB 8
#define U 45
#define FH 128
#define KPAD 48        // padded row length (elems) for bf16 hi/lo buffers
#define TOPC 64        // screened candidate count (rescreened exactly)
#define SSPLIT 4       // s-range slices for qkmax
constexpr float LN_EPS = 1e-12f;

typedef __attribute__((ext_vector_type(8))) short short8v;   // 8 x bf16
typedef __attribute__((ext_vector_type(4))) float float4v;   // MFMA C/D

// ---------------------------------------------------------------------------
// Kernel 1: split-bf16 conversion.
//   z=0: Xh/Xl[b][l][0..47]  = hi/lo(x[b][l][d])  (row-major, zero-padded)
//   z=1: Kh/Kl[b][s][0..47]  = hi/lo(x[b][idx[s]][d]) + per-chunk Ksum partials
// ---------------------------------------------------------------------------
__global__ __launch_bounds__(256) void convert_kernel(const float* __restrict__ x,
                                                      const int* __restrict__ idx,
                                                      ushort* __restrict__ Xh, ushort* __restrict__ Xl,
                                                      ushort* __restrict__ Kh, ushort* __restrict__ Kl,
                                                      float* __restrict__ Ksump) {
  const int c = blockIdx.x, b = blockIdx.y, z = blockIdx.z;
  const int tid = threadIdx.x;
  const int r0 = c * 256;
  const float* xb = x + (size_t)b * LSEQ * D;
  ushort* dh = (z == 0 ? Xh : Kh) + ((size_t)b * LSEQ + r0) * KPAD;
  ushort* dl = (z == 0 ? Xl : Kl) + ((size_t)b * LSEQ + r0) * KPAD;
  for (int i = tid; i < 256 * KPAD; i += 256) {
    const int j = i / KPAD, d = i - j * KPAD;
    const int row = (z == 0) ? (r0 + j) : idx[r0 + j];
    const float v = (d < D) ? xb[(size_t)row * D + d] : 0.0f;
    __hip_bfloat16 h = __float2bfloat16(v);
    const float hf = __bfloat162float(h);
    __hip_bfloat16 lo = __float2bfloat16(v - hf);
    dh[i] = reinterpret_cast<ushort&>(h);
    dl[i] = reinterpret_cast<ushort&>(lo);
  }
  if (z == 1) {  // deterministic per-chunk Ksum partial (combined later)
    __shared__ float kp[4][KPAD];
    const int g = tid >> 6, d = tid & 63;
    float acc = 0.f;
    if (d < D)
      for (int j = g; j < 256; j += 4) acc += xb[(size_t)idx[r0 + j] * D + d];
    if (d < KPAD) kp[g][d] = (d < D) ? acc : 0.f;
    __syncthreads();
    if (tid < D)
      Ksump[((size_t)b * 16 + c) * KPAD + tid] =
          kp[0][tid] + kp[1][tid] + kp[2][tid] + kp[3][tid];
  }
}

// ---------------------------------------------------------------------------
// Kernel 2 (HOT): split-bf16 MFMA QK^T row-max.
// Wave computes a 16(l)x16(s) tile per step: 6 x mfma_f32_16x16x32_bf16
// (hihi k0,k1 + hilo k0,k1 + lohi k0,k1), k padded 45->64 with the second
// k-step's lanes g>=2 zero-masked. A/B frags load straight from global
// (L2-resident); running max kept in regs; 16-lane shfl reduce at the end.
// C layout (m89-verified): col=lane&15, row=(lane>>4)*4+reg.
// ---------------------------------------------------------------------------
__global__ __launch_bounds__(256) void qkmax_kernel(const ushort* __restrict__ Xh,
                                                    const ushort* __restrict__ Xl,
                                                    const ushort* __restrict__ Kh,
                                                    const ushort* __restrict__ Kl,
                                                    float* __restrict__ Mpart) {
  const int b = blockIdx.y, sc = blockIdx.z;
  const int tid = threadIdx.x, lane = tid & 63, wv = tid >> 6;
  const int l0 = blockIdx.x * 64 + wv * 16;
  const int g = lane >> 4, r16 = lane & 15;

  // A fragments: row l0+r16, k = 32*kstep + 8g + j
  const ushort* xh = Xh + ((size_t)b * LSEQ + l0 + r16) * KPAD + 8 * g;
  const ushort* xl = Xl + ((size_t)b * LSEQ + l0 + r16) * KPAD + 8 * g;
  short8v Ah0 = *(const short8v*)xh;
  short8v Al0 = *(const short8v*)xl;
  short8v Ah1 = {}, Al1 = {};
  if (g < 2) { Ah1 = *(const short8v*)(xh + 32); Al1 = *(const short8v*)(xl + 32); }

  const size_t srow0 = (size_t)b * LSEQ + sc * (LSEQ / SSPLIT) + r16;
  const ushort* khB = Kh + srow0 * KPAD + 8 * g;
  const ushort* klB = Kl + srow0 * KPAD + 8 * g;

  float m0 = -INFINITY, m1 = -INFINITY, m2 = -INFINITY, m3 = -INFINITY;
#pragma unroll 2
  for (int st = 0; st < (LSEQ / SSPLIT) / 16; ++st) {
    const ushort* kh = khB + st * (16 * KPAD);
    const ushort* kl = klB + st * (16 * KPAD);
    short8v Bh0 = *(const short8v*)kh;
    short8v Bl0 = *(const short8v*)kl;
    short8v Bh1 = {}, Bl1 = {};
    if (g < 2) { Bh1 = *(const short8v*)(kh + 32); Bl1 = *(const short8v*)(kl + 32); }
    float4v acc = {0.f, 0.f, 0.f, 0.f};
    acc = __builtin_amdgcn_mfma_f32_16x16x32_bf16(Ah0, Bh0, acc, 0, 0, 0);
    acc = __builtin_amdgcn_mfma_f32_16x16x32_bf16(Ah1, Bh1, acc, 0, 0, 0);
    acc = __builtin_amdgcn_mfma_f32_16x16x32_bf16(Ah0, Bl0, acc, 0, 0, 0);
    acc = __builtin_amdgcn_mfma_f32_16x16x32_bf16(Ah1, Bl1, acc, 0, 0, 0);
    acc = __builtin_amdgcn_mfma_f32_16x16x32_bf16(Al0, Bh0, acc, 0, 0, 0);
    acc = __builtin_amdgcn_mfma_f32_16x16x32_bf16(Al1, Bh1, acc, 0, 0, 0);
    m0 = fmaxf(m0, acc[0]); m1 = fmaxf(m1, acc[1]);
    m2 = fmaxf(m2, acc[2]); m3 = fmaxf(m3, acc[3]);
  }
  float mr[4] = {m0, m1, m2, m3};
#pragma unroll
  for (int r = 0; r < 4; ++r) {
    float v = mr[r];
    v = fmaxf(v, __shfl_xor(v, 1));
    v = fmaxf(v, __shfl_xor(v, 2));
    v = fmaxf(v, __shfl_xor(v, 4));
    v = fmaxf(v, __shfl_xor(v, 8));
    if (r16 == 0) Mpart[((size_t)sc * NB + b) * LSEQ + l0 + g * 4 + r] = v;
  }
}

// ---------------------------------------------------------------------------
// Kernel 3: Mapx[b][l] = max_sc(Mpart) - dot(x_l, Ksum)/L   (fp32 mean term)
// ---------------------------------------------------------------------------
__global__ __launch_bounds__(256) void meanM_kernel(const float* __restrict__ x,
                                                    const float* __restrict__ Ksump,
                                                    const float* __restrict__ Mpart,
                                                    float* __restrict__ Mapx) {
  __shared__ float ks[KPAD];
  const int c = blockIdx.x, b = blockIdx.y;
  const int tid = threadIdx.x;
  if (tid < KPAD) {
    float s = 0.f;
    if (tid < D)
      for (int cc = 0; cc < 16; ++cc) s += Ksump[((size_t)b * 16 + cc) * KPAD + tid];
    ks[tid] = s;
  }
  __syncthreads();
  const int l = c * 256 + tid;
  const float* xr = x + ((size_t)b * LSEQ + l) * D;
  float dot = 0.f;
  for (int d = 0; d < D; ++d) dot = fmaf(xr[d], ks[d], dot);
  float mx = Mpart[(size_t)b * LSEQ + l];
  for (int sl = 1; sl < SSPLIT; ++sl)
    mx = fmaxf(mx, Mpart[((size_t)sl * NB + b) * LSEQ + l]);
  Mapx[(size_t)b * LSEQ + l] = mx - dot * (1.0f / LSEQ);
}

// ---------------------------------------------------------------------------
// Kernel 4: radix-select the top-64 candidate SET by approximate M.
// (Set is deterministic; order within Cand need not be.)
// ---------------------------------------------------------------------------
__global__ __launch_bounds__(256) void topk_kernel(const float* __restrict__ Mapx,
                                                   int* __restrict__ Cand) {
  __shared__ int hist[256];
  __shared__ int wsum[4];
  __shared__ int bin_s, need_s, cntG_s, cntEq_s, minv_s;
  __shared__ int eqIdx[LSEQ];
  const int b = blockIdx.x;
  const int tid = threadIdx.x;
  const int lane = tid & 63, wv = tid >> 6;
  uint32_t kreg[16];
#pragma unroll
  for (int k2 = 0; k2 < 16; ++k2) {
    const int l = tid + (k2 << 8);
    uint32_t u = __float_as_uint(Mapx[(size_t)b * LSEQ + l]);
    u ^= (u & 0x80000000u) ? 0xFFFFFFFFu : 0x80000000u;
    kreg[k2] = u;
  }
  const uint32_t pmaskA[4] = {0u, 0xFF000000u, 0xFFFF0000u, 0xFFFFFF00u};
  uint32_t P = 0;
  int need = TOPC;
#pragma unroll
  for (int r = 0; r < 4; ++r) {
    const int shift = 24 - 8 * r;
    hist[tid] = 0;
    __syncthreads();
#pragma unroll
    for (int k2 = 0; k2 < 16; ++k2) {
      const uint32_t key = kreg[k2];
      if (((key ^ P) & pmaskA[r]) == 0) atomicAdd(&hist[(key >> shift) & 0xFF], 1);
    }
    __syncthreads();
    const int h = hist[255 - tid];
    int s = h;
#pragma unroll
    for (int off = 1; off < 64; off <<= 1) {
      int t2 = __shfl_up(s, off);
      if (lane >= off) s += t2;
    }
    if (lane == 63) wsum[wv] = s;
    __syncthreads();
    for (int w2 = 0; w2 < wv; ++w2) s += wsum[w2];
    const int above = s - h;
    if (above < need && s >= need) { bin_s = 255 - tid; need_s = need - above; }
    __syncthreads();
    P |= ((uint32_t)bin_s) << shift;
    need = need_s;
    __syncthreads();
  }
  const uint32_t T = P;

  if (tid == 0) { cntG_s = 0; cntEq_s = 0; }
  __syncthreads();
#pragma unroll
  for (int k2 = 0; k2 < 16; ++k2) {
    const uint32_t key = kreg[k2];
    const int l = tid + (k2 << 8);
    if (key > T) {
      Cand[b * TOPC + atomicAdd(&cntG_s, 1)] = l;
    } else if (key == T) {
      eqIdx[atomicAdd(&cntEq_s, 1)] = l;
    }
  }
  __syncthreads();
  const int G = cntG_s;
  const int nEq = cntEq_s;
  for (int j = 0; j < need; ++j) {
    int mv2 = 0x7FFFFFFF;
    for (int i = tid; i < nEq; i += 256) mv2 = min(mv2, eqIdx[i]);
#pragma unroll
    for (int off = 32; off; off >>= 1) mv2 = min(mv2, __shfl_xor(mv2, off));
    if (lane == 0) wsum[wv] = mv2;
    __syncthreads();
    if (tid == 0) {
      int m2 = min(min(wsum[0], wsum[1]), min(wsum[2], wsum[3]));
      Cand[b * TOPC + G + j] = m2;
      minv_s = m2;
    }
    __syncthreads();
    for (int i = tid; i < nEq; i += 256)
      if (eqIdx[i] == minv_s) eqIdx[i] = 0x7FFFFFFF;
    __syncthreads();
  }
}

// ---------------------------------------------------------------------------
// Kernel 5: exact fp32 rescreen — per 256-key chunk, Mcp[b][c][u] =
// max_s dot(q_cand_u, k_s). K chunk staged in LDS (broadcast reads).
// ---------------------------------------------------------------------------
__global__ __launch_bounds__(256) void rescreen_kernel(const float* __restrict__ x,
                                                       const int* __restrict__ idx,
                                                       const int* __restrict__ Cand,
                                                       float* __restrict__ Mcp) {
  __shared__ float Kr[256][KPAD];
  __shared__ float mred[4][TOPC];
  __shared__ int cl[TOPC];
  const int c = blockIdx.x, b = blockIdx.y;
  const int tid = threadIdx.x;
  const float* xb = x + (size_t)b * LSEQ * D;
  if (tid < TOPC) cl[tid] = Cand[b * TOPC + tid];
  for (int i = tid; i < 256 * D; i += 256) {
    const int j = i / D, d = i - j * D;
    Kr[j][d] = xb[(size_t)idx[c * 256 + j] * D + d];
  }
  __syncthreads();
  const int u = tid & 63, sub = tid >> 6;
  const float* qr = xb + (size_t)cl[u] * D;
  float q[D];
#pragma unroll
  for (int d = 0; d < D; ++d) q[d] = qr[d];
  float mm = -INFINITY;
  for (int s = sub * 64; s < sub * 64 + 64; ++s) {
    float a0 = 0.f, a1 = 0.f;
#pragma unroll
    for (int d = 0; d < 44; d += 4) {
      a0 = fmaf(q[d + 0], Kr[s][d + 0], a0);
      a1 = fmaf(q[d + 1], Kr[s][d + 1], a1);
      a0 = fmaf(q[d + 2], Kr[s][d + 2], a0);
      a1 = fmaf(q[d + 3], Kr[s][d + 3], a1);
    }
    a0 = fmaf(q[44], Kr[s][44], a0);
    mm = fmaxf(mm, a0 + a1);
  }
  mred[sub][u] = mm;
  __syncthreads();
  if (tid < TOPC)
    Mcp[((size_t)b * 16 + c) * TOPC + tid] =
        fmaxf(fmaxf(mred[0][tid], mred[1][tid]), fmaxf(mred[2][tid], mred[3][tid]));
}

// ---------------------------------------------------------------------------
// Kernel 6: exact top-45 among the 64 candidates (value desc, index asc —
// jax.lax.top_k tie order) and gather Qg.
// ---------------------------------------------------------------------------
__global__ __launch_bounds__(256) void select_kernel(const float* __restrict__ x,
                                                     const float* __restrict__ Ksump,
                                                     const int* __restrict__ Cand,
                                                     const float* __restrict__ Mcp,
                                                     float* __restrict__ Qg) {
  __shared__ float ks[KPAD];
  __shared__ unsigned long long keys[TOPC];
  __shared__ int sel[U];
  const int b = blockIdx.x;
  const int tid = threadIdx.x;
  if (tid < KPAD) {
    float s = 0.f;
    if (tid < D)
      for (int cc = 0; cc < 16; ++cc) s += Ksump[((size_t)b * 16 + cc) * KPAD + tid];
    ks[tid] = s;
  }
  __syncthreads();
  if (tid < TOPC) {
    const int l = Cand[b * TOPC + tid];
    float mx = -INFINITY;
    for (int c = 0; c < 16; ++c) mx = fmaxf(mx, Mcp[((size_t)b * 16 + c) * TOPC + tid]);
    const float* xr = x + ((size_t)b * LSEQ + l) * D;
    float dot = 0.f;
    for (int d = 0; d < D; ++d) dot = fmaf(xr[d], ks[d], dot);
    const float Mv = mx - dot * (1.0f / LSEQ);
    uint32_t u = __float_as_uint(Mv);
    u ^= (u & 0x80000000u) ? 0xFFFFFFFFu : 0x80000000u;
    keys[tid] = ((unsigned long long)u << 32) | (unsigned long long)(4095 - l);
  }
  __syncthreads();
  if (tid < TOPC) {
    const unsigned long long ku = keys[tid];
    int rank = 0;
    for (int v = 0; v < TOPC; ++v) rank += (keys[v] > ku);
    if (rank < U) sel[rank] = 4095 - (int)(ku & 0xFFFFFFFFull);
  }
  __syncthreads();
  const float* xb = x + (size_t)b * LSEQ * D;
  for (int i = tid; i < U * D; i += 256) {
    const int u2 = i / D, d = i - u2 * D;
    Qg[(size_t)b * U * D + i] = xb[(size_t)sel[u2] * D + d];
  }
}

// ---------------------------------------------------------------------------
// Kernel 7: sparse attention, chunked-parallel (unchanged, passing).
// ---------------------------------------------------------------------------
__global__ void attn_pv_kernel(const float* __restrict__ x, const float* __restrict__ Qg,
                               float* __restrict__ PVpart) {
  __shared__ float Xs[256][D + 2];
  __shared__ float eS[256][U + 1];
  const int chunk = blockIdx.x, b = blockIdx.y;
  const int tid = threadIdx.x;
  const int l0 = chunk * 256;
  const float* xb = x + ((size_t)b * LSEQ + l0) * D;
  for (int i = tid; i < 256 * D; i += 256) {
    int l = i / D, d = i - l * D;
    Xs[l][d] = xb[i];
  }
  Xs[tid][D] = 1.0f;
  __syncthreads();

  float xr[D];
#pragma unroll
  for (int d = 0; d < D; ++d) xr[d] = Xs[tid][d];
  const float scale = 0.14907119849998599f;  // 1/sqrt(45)
  const float* qb = Qg + (size_t)b * U * D;
  for (int u = 0; u < U; ++u) {
    float acc = 0.f;
#pragma unroll
    for (int d = 0; d < D; ++d) acc = fmaf(qb[u * D + d], xr[d], acc);
    eS[tid][u] = __expf(acc * scale);
  }
  __syncthreads();

  float* outp = PVpart + (size_t)(b * 16 + chunk) * (U * (D + 1));
  for (int idx2 = tid; idx2 < U * (D + 1); idx2 += 256) {
    int u = idx2 / (D + 1), c = idx2 - u * (D + 1);
    float acc = 0.f;
#pragma unroll 4
    for (int l = 0; l < 256; ++l) acc = fmaf(eS[l][u], Xs[l][c], acc);
    outp[idx2] = acc;
  }
}

// ---------------------------------------------------------------------------
// Kernel 8: combine PV partials -> LN1 -> FFN -> LN2 -> out (unchanged).
// ---------------------------------------------------------------------------
__global__ void epilogue_kernel(const float* __restrict__ PVpart,
                                const float* __restrict__ W1, const float* __restrict__ b1,
                                const float* __restrict__ W2, const float* __restrict__ b2,
                                const float* __restrict__ g1, const float* __restrict__ be1,
                                const float* __restrict__ g2, const float* __restrict__ be2,
                                float* __restrict__ out) {
  __shared__ float hA[D][46];
  __shared__ float den[U];
  __shared__ float Wbuf[FH * D];
  __shared__ float f1s[D][FH + 1];
  __shared__ float f2T[D][46];
  const int b = blockIdx.x;
  const int tid = threadIdx.x;
  const float* PV = PVpart + (size_t)b * 16 * U * (D + 1);
  if (tid < U) {
    float s = 0.f;
    for (int c = 0; c < 16; ++c) s += PV[(size_t)c * U * (D + 1) + tid * (D + 1) + D];
    den[tid] = 1.0f / s;
  }
  for (int i = tid; i < FH * D; i += 256) Wbuf[i] = W1[i];
  __syncthreads();
  for (int i = tid; i < U * D; i += 256) {
    int u = i / D, d = i - u * D;
    float s = 0.f;
    for (int c = 0; c < 16; ++c) s += PV[(size_t)c * U * (D + 1) + u * (D + 1) + d];
    hA[u][d] = s * den[u];
  }
  __syncthreads();
  if (tid < U) {
    const int u = tid;
    float mean = 0.f;
    for (int d = 0; d < D; ++d) mean += hA[u][d];
    mean *= (1.0f / D);
    float var = 0.f;
    for (int d = 0; d < D; ++d) { float t = hA[u][d] - mean; var += t * t; }
    var *= (1.0f / D);
    const float inv = 1.0f / sqrtf(var + LN_EPS);
    for (int d = 0; d < D; ++d) hA[u][d] = g1[d] * ((hA[u][d] - mean) * inv) + be1[d];
  }
  __syncthreads();
  for (int i = tid; i < D * FH; i += 256) {
    const int d = i >> 7, hh = i & 127;
    float acc = b1[hh];
    for (int uu = 0; uu < U; ++uu) acc = fmaf(hA[uu][d], Wbuf[hh * D + uu], acc);
    f1s[d][hh] = fmaxf(acc, 0.f);
  }
  __syncthreads();
  for (int i = tid; i < U * FH; i += 256) Wbuf[i] = W2[i];
  __syncthreads();
  for (int i = tid; i < U * D; i += 256) {
    const int u = i / D, d = i - u * D;
    float acc = b2[u];
    for (int h = 0; h < FH; ++h) acc = fmaf(f1s[d][h], Wbuf[u * FH + h], acc);
    f2T[u][d] = acc;
  }
  __syncthreads();
  if (tid < U) {
    const int u = tid;
    float mean = 0.f;
    for (int d = 0; d < D; ++d) mean += f2T[u][d];
    mean *= (1.0f / D);
    float var = 0.f;
    for (int d = 0; d < D; ++d) { float t = f2T[u][d] - mean; var += t * t; }
    var *= (1.0f / D);
    const float inv = 1.0f / sqrtf(var + LN_EPS);
    float* ob = out + ((size_t)b * U + u) * D;
    for (int d = 0; d < D; ++d) ob[d] = g2[d] * ((f2T[u][d] - mean) * inv) + be2[d];
  }
}

// ---------------------------------------------------------------------------
extern "C" void kernel_launch(void* const* d_in, const int* in_sizes, int n_in,
                              void* d_out, int out_size, void* d_ws, size_t ws_size,
                              hipStream_t stream) {
  const float* x = (const float*)d_in[0];
  const float* W1 = (const float*)d_in[1];
  const float* b1 = (const float*)d_in[2];
  const float* W2 = (const float*)d_in[3];
  const float* b2 = (const float*)d_in[4];
  const float* g1 = (const float*)d_in[5];
  const float* be1 = (const float*)d_in[6];
  const float* g2 = (const float*)d_in[7];
  const float* be2 = (const float*)d_in[8];
  const int* idx = (const int*)d_in[9];
  float* out = (float*)d_out;

  // ws layout: Xh|Xl|Kh|Kl (bf16, 12.6MB) | Ksump | Mpart | Mapx | Cand |
  //            Mcp | Qg | PVpart   (~14.4 MiB total)
  const size_t NBF = (size_t)NB * LSEQ * KPAD;  // elems per bf16 buffer
  char* w = (char*)d_ws;
  ushort* Xh = (ushort*)w;
  ushort* Xl = Xh + NBF;
  ushort* Kh = Xl + NBF;
  ushort* Kl = Kh + NBF;
  float* Ksump = (float*)(Kl + NBF);
  float* Mpart = Ksump + (size_t)NB * 16 * KPAD;
  float* Mapx = Mpart + (size_t)SSPLIT * NB * LSEQ;
  int* Cand = (int*)(Mapx + (size_t)NB * LSEQ);
  float* Mcp = (float*)(Cand + NB * TOPC);
  float* Qg = Mcp + (size_t)NB * 16 * TOPC;
  float* PVpart = Qg + (size_t)NB * U * D;

  convert_kernel<<<dim3(16, NB, 2), 256, 0, stream>>>(x, idx, Xh, Xl, Kh, Kl, Ksump);
  qkmax_kernel<<<dim3(LSEQ / 64, NB, SSPLIT), 256, 0, stream>>>(Xh, Xl, Kh, Kl, Mpart);
  meanM_kernel<<<dim3(16, NB), 256, 0, stream>>>(x, Ksump, Mpart, Mapx);
  topk_kernel<<<dim3(NB), 256, 0, stream>>>(Mapx, Cand);
  rescreen_kernel<<<dim3(16, NB), 256, 0, stream>>>(x, idx, Cand, Mcp);
  select_kernel<<<dim3(NB), 256, 0, stream>>>(x, Ksump, Cand, Mcp, Qg);
  attn_pv_kernel<<<dim3(16, NB), 256, 0, stream>>>(x, Qg, PVpart);
  epilogue_kernel<<<dim3(NB), 256, 0, stream>>>(PVpart, W1, b1, W2, b2, g1, be1, g2, be2, out);
}

// Round 7
// 204.576 us; speedup vs baseline: 1.7403x; 1.1495x over previous
//
#include <hip/hip_runtime.h>
#include <hip/hip_bf16.h>

#define D 45
#define LSEQ 4096
#define NB 8
#define U 45
#define FH 128
#define KPAD 48        // padded row length (elems) for bf16 hi/lo buffers
#define TOPC 64        // screened candidate count (rescreened exactly)
#define SSPLIT 8       // s-range slices for qkmax
constexpr float LN_EPS = 1e-12f;

typedef __attribute__((ext_vector_type(8))) short short8v;   // 8 x bf16
typedef __attribute__((ext_vector_type(4))) float float4v;   // MFMA C/D

// ---------------------------------------------------------------------------
// Kernel 1: split-bf16 conversion.
//   z=0: Xh/Xl[b][l][0..47]  = hi/lo(x[b][l][d])  (row-major, zero-padded)
//   z=1: Kh/Kl[b][s][0..47]  = hi/lo(x[b][idx[s]][d]) + per-chunk Ksum partials
// ---------------------------------------------------------------------------
__global__ __launch_bounds__(256) void convert_kernel(const float* __restrict__ x,
                                                      const int* __restrict__ idx,
                                                      ushort* __restrict__ Xh, ushort* __restrict__ Xl,
                                                      ushort* __restrict__ Kh, ushort* __restrict__ Kl,
                                                      float* __restrict__ Ksump) {
  const int c = blockIdx.x, b = blockIdx.y, z = blockIdx.z;
  const int tid = threadIdx.x;
  const int r0 = c * 256;
  const float* xb = x + (size_t)b * LSEQ * D;
  ushort* dh = (z == 0 ? Xh : Kh) + ((size_t)b * LSEQ + r0) * KPAD;
  ushort* dl = (z == 0 ? Xl : Kl) + ((size_t)b * LSEQ + r0) * KPAD;
  for (int i = tid; i < 256 * KPAD; i += 256) {
    const int j = i / KPAD, d = i - j * KPAD;
    const int row = (z == 0) ? (r0 + j) : idx[r0 + j];
    const float v = (d < D) ? xb[(size_t)row * D + d] : 0.0f;
    __hip_bfloat16 h = __float2bfloat16(v);
    const float hf = __bfloat162float(h);
    __hip_bfloat16 lo = __float2bfloat16(v - hf);
    dh[i] = reinterpret_cast<ushort&>(h);
    dl[i] = reinterpret_cast<ushort&>(lo);
  }
  if (z == 1) {  // deterministic per-chunk Ksum partial (combined later)
    __shared__ float kp[4][KPAD];
    const int g = tid >> 6, d = tid & 63;
    float acc = 0.f;
    if (d < D)
      for (int j = g; j < 256; j += 4) acc += xb[(size_t)idx[r0 + j] * D + d];
    if (d < KPAD) kp[g][d] = (d < D) ? acc : 0.f;
    __syncthreads();
    if (tid < D)
      Ksump[((size_t)b * 16 + c) * KPAD + tid] =
          kp[0][tid] + kp[1][tid] + kp[2][tid] + kp[3][tid];
  }
}

// ---------------------------------------------------------------------------
// Kernel 2 (HOT): split-bf16 MFMA QK^T row-max, 4 l-tiles per wave.
// A-fragments for 4 tiles (64 rows) hoisted to registers; each B-fragment
// load from L2 now feeds 24 MFMAs (4x reuse vs round 6) and the 4 acc
// chains give the MFMA pipe ILP. C layout: col=lane&15, row=(lane>>4)*4+reg.
// ---------------------------------------------------------------------------
__global__ __launch_bounds__(256) void qkmax_kernel(const ushort* __restrict__ Xh,
                                                    const ushort* __restrict__ Xl,
                                                    const ushort* __restrict__ Kh,
                                                    const ushort* __restrict__ Kl,
                                                    float* __restrict__ Mpart) {
  const int b = blockIdx.y, sc = blockIdx.z;
  const int tid = threadIdx.x, lane = tid & 63, wv = tid >> 6;
  const int l0 = blockIdx.x * 256 + wv * 64;  // wave's 64 q-rows
  const int g = lane >> 4, r16 = lane & 15;

  // A fragments: 4 l-tiles, row = l0 + lt*16 + r16, k = 32*kstep + 8g + j
  short8v Ah0[4], Al0[4], Ah1[4], Al1[4];
#pragma unroll
  for (int lt = 0; lt < 4; ++lt) {
    const ushort* xh = Xh + ((size_t)b * LSEQ + l0 + lt * 16 + r16) * KPAD + 8 * g;
    const ushort* xl = Xl + ((size_t)b * LSEQ + l0 + lt * 16 + r16) * KPAD + 8 * g;
    Ah0[lt] = *(const short8v*)xh;
    Al0[lt] = *(const short8v*)xl;
    Ah1[lt] = {};
    Al1[lt] = {};
    if (g < 2) { Ah1[lt] = *(const short8v*)(xh + 32); Al1[lt] = *(const short8v*)(xl + 32); }
  }

  const size_t srow0 = (size_t)b * LSEQ + sc * (LSEQ / SSPLIT) + r16;
  const ushort* khB = Kh + srow0 * KPAD + 8 * g;
  const ushort* klB = Kl + srow0 * KPAD + 8 * g;

  float mx[4][4];
#pragma unroll
  for (int lt = 0; lt < 4; ++lt)
#pragma unroll
    for (int r = 0; r < 4; ++r) mx[lt][r] = -INFINITY;

#pragma unroll 2
  for (int st = 0; st < (LSEQ / SSPLIT) / 16; ++st) {
    const ushort* kh = khB + st * (16 * KPAD);
    const ushort* kl = klB + st * (16 * KPAD);
    short8v Bh0 = *(const short8v*)kh;
    short8v Bl0 = *(const short8v*)kl;
    short8v Bh1 = {}, Bl1 = {};
    if (g < 2) { Bh1 = *(const short8v*)(kh + 32); Bl1 = *(const short8v*)(kl + 32); }
#pragma unroll
    for (int lt = 0; lt < 4; ++lt) {
      float4v acc = {0.f, 0.f, 0.f, 0.f};
      acc = __builtin_amdgcn_mfma_f32_16x16x32_bf16(Ah0[lt], Bh0, acc, 0, 0, 0);
      acc = __builtin_amdgcn_mfma_f32_16x16x32_bf16(Ah1[lt], Bh1, acc, 0, 0, 0);
      acc = __builtin_amdgcn_mfma_f32_16x16x32_bf16(Ah0[lt], Bl0, acc, 0, 0, 0);
      acc = __builtin_amdgcn_mfma_f32_16x16x32_bf16(Ah1[lt], Bl1, acc, 0, 0, 0);
      acc = __builtin_amdgcn_mfma_f32_16x16x32_bf16(Al0[lt], Bh0, acc, 0, 0, 0);
      acc = __builtin_amdgcn_mfma_f32_16x16x32_bf16(Al1[lt], Bh1, acc, 0, 0, 0);
      mx[lt][0] = fmaxf(mx[lt][0], acc[0]);
      mx[lt][1] = fmaxf(mx[lt][1], acc[1]);
      mx[lt][2] = fmaxf(mx[lt][2], acc[2]);
      mx[lt][3] = fmaxf(mx[lt][3], acc[3]);
    }
  }

#pragma unroll
  for (int lt = 0; lt < 4; ++lt)
#pragma unroll
    for (int r = 0; r < 4; ++r) {
      float v = mx[lt][r];
      v = fmaxf(v, __shfl_xor(v, 1));
      v = fmaxf(v, __shfl_xor(v, 2));
      v = fmaxf(v, __shfl_xor(v, 4));
      v = fmaxf(v, __shfl_xor(v, 8));
      if (r16 == 0)
        Mpart[((size_t)sc * NB + b) * LSEQ + l0 + lt * 16 + g * 4 + r] = v;
    }
}

// ---------------------------------------------------------------------------
// Kernel 3: Mapx[b][l] = max_sc(Mpart) - dot(x_l, Ksum)/L   (fp32 mean term)
// ---------------------------------------------------------------------------
__global__ __launch_bounds__(256) void meanM_kernel(const float* __restrict__ x,
                                                    const float* __restrict__ Ksump,
                                                    const float* __restrict__ Mpart,
                                                    float* __restrict__ Mapx) {
  __shared__ float ks[KPAD];
  const int c = blockIdx.x, b = blockIdx.y;
  const int tid = threadIdx.x;
  if (tid < KPAD) {
    float s = 0.f;
    if (tid < D)
      for (int cc = 0; cc < 16; ++cc) s += Ksump[((size_t)b * 16 + cc) * KPAD + tid];
    ks[tid] = s;
  }
  __syncthreads();
  const int l = c * 256 + tid;
  const float* xr = x + ((size_t)b * LSEQ + l) * D;
  float dot = 0.f;
  for (int d = 0; d < D; ++d) dot = fmaf(xr[d], ks[d], dot);
  float mx = Mpart[(size_t)b * LSEQ + l];
  for (int sl = 1; sl < SSPLIT; ++sl)
    mx = fmaxf(mx, Mpart[((size_t)sl * NB + b) * LSEQ + l]);
  Mapx[(size_t)b * LSEQ + l] = mx - dot * (1.0f / LSEQ);
}

// ---------------------------------------------------------------------------
// Kernel 4: radix-select the top-64 candidate SET by approximate M.
// ---------------------------------------------------------------------------
__global__ __launch_bounds__(256) void topk_kernel(const float* __restrict__ Mapx,
                                                   int* __restrict__ Cand) {
  __shared__ int hist[256];
  __shared__ int wsum[4];
  __shared__ int bin_s, need_s, cntG_s, cntEq_s, minv_s;
  __shared__ int eqIdx[LSEQ];
  const int b = blockIdx.x;
  const int tid = threadIdx.x;
  const int lane = tid & 63, wv = tid >> 6;
  uint32_t kreg[16];
#pragma unroll
  for (int k2 = 0; k2 < 16; ++k2) {
    const int l = tid + (k2 << 8);
    uint32_t u = __float_as_uint(Mapx[(size_t)b * LSEQ + l]);
    u ^= (u & 0x80000000u) ? 0xFFFFFFFFu : 0x80000000u;
    kreg[k2] = u;
  }
  const uint32_t pmaskA[4] = {0u, 0xFF000000u, 0xFFFF0000u, 0xFFFFFF00u};
  uint32_t P = 0;
  int need = TOPC;
#pragma unroll
  for (int r = 0; r < 4; ++r) {
    const int shift = 24 - 8 * r;
    hist[tid] = 0;
    __syncthreads();
#pragma unroll
    for (int k2 = 0; k2 < 16; ++k2) {
      const uint32_t key = kreg[k2];
      if (((key ^ P) & pmaskA[r]) == 0) atomicAdd(&hist[(key >> shift) & 0xFF], 1);
    }
    __syncthreads();
    const int h = hist[255 - tid];
    int s = h;
#pragma unroll
    for (int off = 1; off < 64; off <<= 1) {
      int t2 = __shfl_up(s, off);
      if (lane >= off) s += t2;
    }
    if (lane == 63) wsum[wv] = s;
    __syncthreads();
    for (int w2 = 0; w2 < wv; ++w2) s += wsum[w2];
    const int above = s - h;
    if (above < need && s >= need) { bin_s = 255 - tid; need_s = need - above; }
    __syncthreads();
    P |= ((uint32_t)bin_s) << shift;
    need = need_s;
    __syncthreads();
  }
  const uint32_t T = P;

  if (tid == 0) { cntG_s = 0; cntEq_s = 0; }
  __syncthreads();
#pragma unroll
  for (int k2 = 0; k2 < 16; ++k2) {
    const uint32_t key = kreg[k2];
    const int l = tid + (k2 << 8);
    if (key > T) {
      Cand[b * TOPC + atomicAdd(&cntG_s, 1)] = l;
    } else if (key == T) {
      eqIdx[atomicAdd(&cntEq_s, 1)] = l;
    }
  }
  __syncthreads();
  const int G = cntG_s;
  const int nEq = cntEq_s;
  for (int j = 0; j < need; ++j) {
    int mv2 = 0x7FFFFFFF;
    for (int i = tid; i < nEq; i += 256) mv2 = min(mv2, eqIdx[i]);
#pragma unroll
    for (int off = 32; off; off >>= 1) mv2 = min(mv2, __shfl_xor(mv2, off));
    if (lane == 0) wsum[wv] = mv2;
    __syncthreads();
    if (tid == 0) {
      int m2 = min(min(wsum[0], wsum[1]), min(wsum[2], wsum[3]));
      Cand[b * TOPC + G + j] = m2;
      minv_s = m2;
    }
    __syncthreads();
    for (int i = tid; i < nEq; i += 256)
      if (eqIdx[i] == minv_s) eqIdx[i] = 0x7FFFFFFF;
    __syncthreads();
  }
}

// ---------------------------------------------------------------------------
// Kernel 5: exact fp32 rescreen — per 256-key chunk, Mcp[b][c][u] =
// max_s dot(q_cand_u, k_s). K chunk staged in LDS (broadcast reads).
// ---------------------------------------------------------------------------
__global__ __launch_bounds__(256) void rescreen_kernel(const float* __restrict__ x,
                                                       const int* __restrict__ idx,
                                                       const int* __restrict__ Cand,
                                                       float* __restrict__ Mcp) {
  __shared__ float Kr[256][KPAD];
  __shared__ float mred[4][TOPC];
  __shared__ int cl[TOPC];
  const int c = blockIdx.x, b = blockIdx.y;
  const int tid = threadIdx.x;
  const float* xb = x + (size_t)b * LSEQ * D;
  if (tid < TOPC) cl[tid] = Cand[b * TOPC + tid];
  for (int i = tid; i < 256 * D; i += 256) {
    const int j = i / D, d = i - j * D;
    Kr[j][d] = xb[(size_t)idx[c * 256 + j] * D + d];
  }
  __syncthreads();
  const int u = tid & 63, sub = tid >> 6;
  const float* qr = xb + (size_t)cl[u] * D;
  float q[D];
#pragma unroll
  for (int d = 0; d < D; ++d) q[d] = qr[d];
  float mm = -INFINITY;
  for (int s = sub * 64; s < sub * 64 + 64; ++s) {
    float a0 = 0.f, a1 = 0.f;
#pragma unroll
    for (int d = 0; d < 44; d += 4) {
      a0 = fmaf(q[d + 0], Kr[s][d + 0], a0);
      a1 = fmaf(q[d + 1], Kr[s][d + 1], a1);
      a0 = fmaf(q[d + 2], Kr[s][d + 2], a0);
      a1 = fmaf(q[d + 3], Kr[s][d + 3], a1);
    }
    a0 = fmaf(q[44], Kr[s][44], a0);
    mm = fmaxf(mm, a0 + a1);
  }
  mred[sub][u] = mm;
  __syncthreads();
  if (tid < TOPC)
    Mcp[((size_t)b * 16 + c) * TOPC + tid] =
        fmaxf(fmaxf(mred[0][tid], mred[1][tid]), fmaxf(mred[2][tid], mred[3][tid]));
}

// ---------------------------------------------------------------------------
// Kernel 6: exact top-45 among the 64 candidates (value desc, index asc —
// jax.lax.top_k tie order) and gather Qg.
// ---------------------------------------------------------------------------
__global__ __launch_bounds__(256) void select_kernel(const float* __restrict__ x,
                                                     const float* __restrict__ Ksump,
                                                     const int* __restrict__ Cand,
                                                     const float* __restrict__ Mcp,
                                                     float* __restrict__ Qg) {
  __shared__ float ks[KPAD];
  __shared__ unsigned long long keys[TOPC];
  __shared__ int sel[U];
  const int b = blockIdx.x;
  const int tid = threadIdx.x;
  if (tid < KPAD) {
    float s = 0.f;
    if (tid < D)
      for (int cc = 0; cc < 16; ++cc) s += Ksump[((size_t)b * 16 + cc) * KPAD + tid];
    ks[tid] = s;
  }
  __syncthreads();
  if (tid < TOPC) {
    const int l = Cand[b * TOPC + tid];
    float mx = -INFINITY;
    for (int c = 0; c < 16; ++c) mx = fmaxf(mx, Mcp[((size_t)b * 16 + c) * TOPC + tid]);
    const float* xr = x + ((size_t)b * LSEQ + l) * D;
    float dot = 0.f;
    for (int d = 0; d < D; ++d) dot = fmaf(xr[d], ks[d], dot);
    const float Mv = mx - dot * (1.0f / LSEQ);
    uint32_t u = __float_as_uint(Mv);
    u ^= (u & 0x80000000u) ? 0xFFFFFFFFu : 0x80000000u;
    keys[tid] = ((unsigned long long)u << 32) | (unsigned long long)(4095 - l);
  }
  __syncthreads();
  if (tid < TOPC) {
    const unsigned long long ku = keys[tid];
    int rank = 0;
    for (int v = 0; v < TOPC; ++v) rank += (keys[v] > ku);
    if (rank < U) sel[rank] = 4095 - (int)(ku & 0xFFFFFFFFull);
  }
  __syncthreads();
  const float* xb = x + (size_t)b * LSEQ * D;
  for (int i = tid; i < U * D; i += 256) {
    const int u2 = i / D, d = i - u2 * D;
    Qg[(size_t)b * U * D + i] = xb[(size_t)sel[u2] * D + d];
  }
}

// ---------------------------------------------------------------------------
// Kernel 7: sparse attention, chunked-parallel (unchanged, passing).
// ---------------------------------------------------------------------------
__global__ void attn_pv_kernel(const float* __restrict__ x, const float* __restrict__ Qg,
                               float* __restrict__ PVpart) {
  __shared__ float Xs[256][D + 2];
  __shared__ float eS[256][U + 1];
  const int chunk = blockIdx.x, b = blockIdx.y;
  const int tid = threadIdx.x;
  const int l0 = chunk * 256;
  const float* xb = x + ((size_t)b * LSEQ + l0) * D;
  for (int i = tid; i < 256 * D; i += 256) {
    int l = i / D, d = i - l * D;
    Xs[l][d] = xb[i];
  }
  Xs[tid][D] = 1.0f;
  __syncthreads();

  float xr[D];
#pragma unroll
  for (int d = 0; d < D; ++d) xr[d] = Xs[tid][d];
  const float scale = 0.14907119849998599f;  // 1/sqrt(45)
  const float* qb = Qg + (size_t)b * U * D;
  for (int u = 0; u < U; ++u) {
    float acc = 0.f;
#pragma unroll
    for (int d = 0; d < D; ++d) acc = fmaf(qb[u * D + d], xr[d], acc);
    eS[tid][u] = __expf(acc * scale);
  }
  __syncthreads();

  float* outp = PVpart + (size_t)(b * 16 + chunk) * (U * (D + 1));
  for (int idx2 = tid; idx2 < U * (D + 1); idx2 += 256) {
    int u = idx2 / (D + 1), c = idx2 - u * (D + 1);
    float acc = 0.f;
#pragma unroll 4
    for (int l = 0; l < 256; ++l) acc = fmaf(eS[l][u], Xs[l][c], acc);
    outp[idx2] = acc;
  }
}

// ---------------------------------------------------------------------------
// Kernel 8: combine PV partials -> LN1 -> FFN -> LN2 -> out (unchanged).
// ---------------------------------------------------------------------------
__global__ void epilogue_kernel(const float* __restrict__ PVpart,
                                const float* __restrict__ W1, const float* __restrict__ b1,
                                const float* __restrict__ W2, const float* __restrict__ b2,
                                const float* __restrict__ g1, const float* __restrict__ be1,
                                const float* __restrict__ g2, const float* __restrict__ be2,
                                float* __restrict__ out) {
  __shared__ float hA[D][46];
  __shared__ float den[U];
  __shared__ float Wbuf[FH * D];
  __shared__ float f1s[D][FH + 1];
  __shared__ float f2T[D][46];
  const int b = blockIdx.x;
  const int tid = threadIdx.x;
  const float* PV = PVpart + (size_t)b * 16 * U * (D + 1);
  if (tid < U) {
    float s = 0.f;
    for (int c = 0; c < 16; ++c) s += PV[(size_t)c * U * (D + 1) + tid * (D + 1) + D];
    den[tid] = 1.0f / s;
  }
  for (int i = tid; i < FH * D; i += 256) Wbuf[i] = W1[i];
  __syncthreads();
  for (int i = tid; i < U * D; i += 256) {
    int u = i / D, d = i - u * D;
    float s = 0.f;
    for (int c = 0; c < 16; ++c) s += PV[(size_t)c * U * (D + 1) + u * (D + 1) + d];
    hA[u][d] = s * den[u];
  }
  __syncthreads();
  if (tid < U) {
    const int u = tid;
    float mean = 0.f;
    for (int d = 0; d < D; ++d) mean += hA[u][d];
    mean *= (1.0f / D);
    float var = 0.f;
    for (int d = 0; d < D; ++d) { float t = hA[u][d] - mean; var += t * t; }
    var *= (1.0f / D);
    const float inv = 1.0f / sqrtf(var + LN_EPS);
    for (int d = 0; d < D; ++d) hA[u][d] = g1[d] * ((hA[u][d] - mean) * inv) + be1[d];
  }
  __syncthreads();
  for (int i = tid; i < D * FH; i += 256) {
    const int d = i >> 7, hh = i & 127;
    float acc = b1[hh];
    for (int uu = 0; uu < U; ++uu) acc = fmaf(hA[uu][d], Wbuf[hh * D + uu], acc);
    f1s[d][hh] = fmaxf(acc, 0.f);
  }
  __syncthreads();
  for (int i = tid; i < U * FH; i += 256) Wbuf[i] = W2[i];
  __syncthreads();
  for (int i = tid; i < U * D; i += 256) {
    const int u = i / D, d = i - u * D;
    float acc = b2[u];
    for (int h = 0; h < FH; ++h) acc = fmaf(f1s[d][h], Wbuf[u * FH + h], acc);
    f2T[u][d] = acc;
  }
  __syncthreads();
  if (tid < U) {
    const int u = tid;
    float mean = 0.f;
    for (int d = 0; d < D; ++d) mean += f2T[u][d];
    mean *= (1.0f / D);
    float var = 0.f;
    for (int d = 0; d < D; ++d) { float t = f2T[u][d] - mean; var += t * t; }
    var *= (1.0f / D);
    const float inv = 1.0f / sqrtf(var + LN_EPS);
    float* ob = out + ((size_t)b * U + u) * D;
    for (int d = 0; d < D; ++d) ob[d] = g2[d] * ((f2T[u][d] - mean) * inv) + be2[d];
  }
}

// ---------------------------------------------------------------------------
extern "C" void kernel_launch(void* const* d_in, const int* in_sizes, int n_in,
                              void* d_out, int out_size, void* d_ws, size_t ws_size,
                              hipStream_t stream) {
  const float* x = (const float*)d_in[0];
  const float* W1 = (const float*)d_in[1];
  const float* b1 = (const float*)d_in[2];
  const float* W2 = (const float*)d_in[3];
  const float* b2 = (const float*)d_in[4];
  const float* g1 = (const float*)d_in[5];
  const float* be1 = (const float*)d_in[6];
  const float* g2 = (const float*)d_in[7];
  const float* be2 = (const float*)d_in[8];
  const int* idx = (const int*)d_in[9];
  float* out = (float*)d_out;

  // ws layout: Xh|Xl|Kh|Kl (bf16, 12.6MB) | Ksump | Mpart | Mapx | Cand |
  //            Mcp | Qg | PVpart   (~15 MiB total)
  const size_t NBF = (size_t)NB * LSEQ * KPAD;  // elems per bf16 buffer
  char* w = (char*)d_ws;
  ushort* Xh = (ushort*)w;
  ushort* Xl = Xh + NBF;
  ushort* Kh = Xl + NBF;
  ushort* Kl = Kh + NBF;
  float* Ksump = (float*)(Kl + NBF);
  float* Mpart = Ksump + (size_t)NB * 16 * KPAD;
  float* Mapx = Mpart + (size_t)SSPLIT * NB * LSEQ;
  int* Cand = (int*)(Mapx + (size_t)NB * LSEQ);
  float* Mcp = (float*)(Cand + NB * TOPC);
  float* Qg = Mcp + (size_t)NB * 16 * TOPC;
  float* PVpart = Qg + (size_t)NB * U * D;

  convert_kernel<<<dim3(16, NB, 2), 256, 0, stream>>>(x, idx, Xh, Xl, Kh, Kl, Ksump);
  qkmax_kernel<<<dim3(LSEQ / 256, NB, SSPLIT), 256, 0, stream>>>(Xh, Xl, Kh, Kl, Mpart);
  meanM_kernel<<<dim3(16, NB), 256, 0, stream>>>(x, Ksump, Mpart, Mapx);
  topk_kernel<<<dim3(NB), 256, 0, stream>>>(Mapx, Cand);
  rescreen_kernel<<<dim3(16, NB), 256, 0, stream>>>(x, idx, Cand, Mcp);
  select_kernel<<<dim3(NB), 256, 0, stream>>>(x, Ksump, Cand, Mcp, Qg);
  attn_pv_kernel<<<dim3(16, NB), 256, 0, stream>>>(x, Qg, PVpart);
  epilogue_kernel<<<dim3(NB), 256, 0, stream>>>(PVpart, W1, b1, W2, b2, g1, be1, g2, be2, out);
}

// Round 8
// 190.675 us; speedup vs baseline: 1.8672x; 1.0729x over previous
//
#include <hip/hip_runtime.h>
#include <hip/hip_bf16.h>

#define D 45
#define LSEQ 4096
#define NB 8
#define U 45
#define FH 128
#define KPAD 48        // padded row length (elems) for bf16 hi/lo buffers
#define TOPC 64        // screened candidate count (rescreened exactly)
#define SSPLIT 8       // s-range slices for qkmax
#define CH 64          // attn_pv rows per chunk
#define NCH (LSEQ / CH)  // 64 chunks
constexpr float LN_EPS = 1e-12f;

typedef __attribute__((ext_vector_type(8))) short short8v;   // 8 x bf16
typedef __attribute__((ext_vector_type(4))) float float4v;   // MFMA C/D

// ---------------------------------------------------------------------------
// Kernel 1: split-bf16 conversion.
//   z=0: Xh/Xl[b][l][0..47]  = hi/lo(x[b][l][d])  (row-major, zero-padded)
//   z=1: Kh/Kl[b][s][0..47]  = hi/lo(x[b][idx[s]][d]) + per-chunk Ksum partials
// ---------------------------------------------------------------------------
__global__ __launch_bounds__(256) void convert_kernel(const float* __restrict__ x,
                                                      const int* __restrict__ idx,
                                                      ushort* __restrict__ Xh, ushort* __restrict__ Xl,
                                                      ushort* __restrict__ Kh, ushort* __restrict__ Kl,
                                                      float* __restrict__ Ksump) {
  const int c = blockIdx.x, b = blockIdx.y, z = blockIdx.z;
  const int tid = threadIdx.x;
  const int r0 = c * 256;
  const float* xb = x + (size_t)b * LSEQ * D;
  ushort* dh = (z == 0 ? Xh : Kh) + ((size_t)b * LSEQ + r0) * KPAD;
  ushort* dl = (z == 0 ? Xl : Kl) + ((size_t)b * LSEQ + r0) * KPAD;
  for (int i = tid; i < 256 * KPAD; i += 256) {
    const int j = i / KPAD, d = i - j * KPAD;
    const int row = (z == 0) ? (r0 + j) : idx[r0 + j];
    const float v = (d < D) ? xb[(size_t)row * D + d] : 0.0f;
    __hip_bfloat16 h = __float2bfloat16(v);
    const float hf = __bfloat162float(h);
    __hip_bfloat16 lo = __float2bfloat16(v - hf);
    dh[i] = reinterpret_cast<ushort&>(h);
    dl[i] = reinterpret_cast<ushort&>(lo);
  }
  if (z == 1) {  // deterministic per-chunk Ksum partial (combined later)
    __shared__ float kp[4][KPAD];
    const int g = tid >> 6, d = tid & 63;
    float acc = 0.f;
    if (d < D)
      for (int j = g; j < 256; j += 4) acc += xb[(size_t)idx[r0 + j] * D + d];
    if (d < KPAD) kp[g][d] = (d < D) ? acc : 0.f;
    __syncthreads();
    if (tid < D)
      Ksump[((size_t)b * 16 + c) * KPAD + tid] =
          kp[0][tid] + kp[1][tid] + kp[2][tid] + kp[3][tid];
  }
}

// ---------------------------------------------------------------------------
// Kernel 2 (HOT): split-bf16 MFMA QK^T row-max, 4 l-tiles per wave.
// ---------------------------------------------------------------------------
__global__ __launch_bounds__(256) void qkmax_kernel(const ushort* __restrict__ Xh,
                                                    const ushort* __restrict__ Xl,
                                                    const ushort* __restrict__ Kh,
                                                    const ushort* __restrict__ Kl,
                                                    float* __restrict__ Mpart) {
  const int b = blockIdx.y, sc = blockIdx.z;
  const int tid = threadIdx.x, lane = tid & 63, wv = tid >> 6;
  const int l0 = blockIdx.x * 256 + wv * 64;  // wave's 64 q-rows
  const int g = lane >> 4, r16 = lane & 15;

  short8v Ah0[4], Al0[4], Ah1[4], Al1[4];
#pragma unroll
  for (int lt = 0; lt < 4; ++lt) {
    const ushort* xh = Xh + ((size_t)b * LSEQ + l0 + lt * 16 + r16) * KPAD + 8 * g;
    const ushort* xl = Xl + ((size_t)b * LSEQ + l0 + lt * 16 + r16) * KPAD + 8 * g;
    Ah0[lt] = *(const short8v*)xh;
    Al0[lt] = *(const short8v*)xl;
    Ah1[lt] = {};
    Al1[lt] = {};
    if (g < 2) { Ah1[lt] = *(const short8v*)(xh + 32); Al1[lt] = *(const short8v*)(xl + 32); }
  }

  const size_t srow0 = (size_t)b * LSEQ + sc * (LSEQ / SSPLIT) + r16;
  const ushort* khB = Kh + srow0 * KPAD + 8 * g;
  const ushort* klB = Kl + srow0 * KPAD + 8 * g;

  float mx[4][4];
#pragma unroll
  for (int lt = 0; lt < 4; ++lt)
#pragma unroll
    for (int r = 0; r < 4; ++r) mx[lt][r] = -INFINITY;

#pragma unroll 2
  for (int st = 0; st < (LSEQ / SSPLIT) / 16; ++st) {
    const ushort* kh = khB + st * (16 * KPAD);
    const ushort* kl = klB + st * (16 * KPAD);
    short8v Bh0 = *(const short8v*)kh;
    short8v Bl0 = *(const short8v*)kl;
    short8v Bh1 = {}, Bl1 = {};
    if (g < 2) { Bh1 = *(const short8v*)(kh + 32); Bl1 = *(const short8v*)(kl + 32); }
#pragma unroll
    for (int lt = 0; lt < 4; ++lt) {
      float4v acc = {0.f, 0.f, 0.f, 0.f};
      acc = __builtin_amdgcn_mfma_f32_16x16x32_bf16(Ah0[lt], Bh0, acc, 0, 0, 0);
      acc = __builtin_amdgcn_mfma_f32_16x16x32_bf16(Ah1[lt], Bh1, acc, 0, 0, 0);
      acc = __builtin_amdgcn_mfma_f32_16x16x32_bf16(Ah0[lt], Bl0, acc, 0, 0, 0);
      acc = __builtin_amdgcn_mfma_f32_16x16x32_bf16(Ah1[lt], Bl1, acc, 0, 0, 0);
      acc = __builtin_amdgcn_mfma_f32_16x16x32_bf16(Al0[lt], Bh0, acc, 0, 0, 0);
      acc = __builtin_amdgcn_mfma_f32_16x16x32_bf16(Al1[lt], Bh1, acc, 0, 0, 0);
      mx[lt][0] = fmaxf(mx[lt][0], acc[0]);
      mx[lt][1] = fmaxf(mx[lt][1], acc[1]);
      mx[lt][2] = fmaxf(mx[lt][2], acc[2]);
      mx[lt][3] = fmaxf(mx[lt][3], acc[3]);
    }
  }

#pragma unroll
  for (int lt = 0; lt < 4; ++lt)
#pragma unroll
    for (int r = 0; r < 4; ++r) {
      float v = mx[lt][r];
      v = fmaxf(v, __shfl_xor(v, 1));
      v = fmaxf(v, __shfl_xor(v, 2));
      v = fmaxf(v, __shfl_xor(v, 4));
      v = fmaxf(v, __shfl_xor(v, 8));
      if (r16 == 0)
        Mpart[((size_t)sc * NB + b) * LSEQ + l0 + lt * 16 + g * 4 + r] = v;
    }
}

// ---------------------------------------------------------------------------
// Kernel 3: Mapx[b][l] = max_sc(Mpart) - dot(x_l, Ksum)/L   (fp32 mean term)
// ---------------------------------------------------------------------------
__global__ __launch_bounds__(256) void meanM_kernel(const float* __restrict__ x,
                                                    const float* __restrict__ Ksump,
                                                    const float* __restrict__ Mpart,
                                                    float* __restrict__ Mapx) {
  __shared__ float ks[KPAD];
  const int c = blockIdx.x, b = blockIdx.y;
  const int tid = threadIdx.x;
  if (tid < KPAD) {
    float s = 0.f;
    if (tid < D)
      for (int cc = 0; cc < 16; ++cc) s += Ksump[((size_t)b * 16 + cc) * KPAD + tid];
    ks[tid] = s;
  }
  __syncthreads();
  const int l = c * 256 + tid;
  const float* xr = x + ((size_t)b * LSEQ + l) * D;
  float dot = 0.f;
  for (int d = 0; d < D; ++d) dot = fmaf(xr[d], ks[d], dot);
  float mx = Mpart[(size_t)b * LSEQ + l];
  for (int sl = 1; sl < SSPLIT; ++sl)
    mx = fmaxf(mx, Mpart[((size_t)sl * NB + b) * LSEQ + l]);
  Mapx[(size_t)b * LSEQ + l] = mx - dot * (1.0f / LSEQ);
}

// ---------------------------------------------------------------------------
// Kernel 4: radix-select the top-64 candidate SET by approximate M.
// ---------------------------------------------------------------------------
__global__ __launch_bounds__(256) void topk_kernel(const float* __restrict__ Mapx,
                                                   int* __restrict__ Cand) {
  __shared__ int hist[256];
  __shared__ int wsum[4];
  __shared__ int bin_s, need_s, cntG_s, cntEq_s, minv_s;
  __shared__ int eqIdx[LSEQ];
  const int b = blockIdx.x;
  const int tid = threadIdx.x;
  const int lane = tid & 63, wv = tid >> 6;
  uint32_t kreg[16];
#pragma unroll
  for (int k2 = 0; k2 < 16; ++k2) {
    const int l = tid + (k2 << 8);
    uint32_t u = __float_as_uint(Mapx[(size_t)b * LSEQ + l]);
    u ^= (u & 0x80000000u) ? 0xFFFFFFFFu : 0x80000000u;
    kreg[k2] = u;
  }
  const uint32_t pmaskA[4] = {0u, 0xFF000000u, 0xFFFF0000u, 0xFFFFFF00u};
  uint32_t P = 0;
  int need = TOPC;
#pragma unroll
  for (int r = 0; r < 4; ++r) {
    const int shift = 24 - 8 * r;
    hist[tid] = 0;
    __syncthreads();
#pragma unroll
    for (int k2 = 0; k2 < 16; ++k2) {
      const uint32_t key = kreg[k2];
      if (((key ^ P) & pmaskA[r]) == 0) atomicAdd(&hist[(key >> shift) & 0xFF], 1);
    }
    __syncthreads();
    const int h = hist[255 - tid];
    int s = h;
#pragma unroll
    for (int off = 1; off < 64; off <<= 1) {
      int t2 = __shfl_up(s, off);
      if (lane >= off) s += t2;
    }
    if (lane == 63) wsum[wv] = s;
    __syncthreads();
    for (int w2 = 0; w2 < wv; ++w2) s += wsum[w2];
    const int above = s - h;
    if (above < need && s >= need) { bin_s = 255 - tid; need_s = need - above; }
    __syncthreads();
    P |= ((uint32_t)bin_s) << shift;
    need = need_s;
    __syncthreads();
  }
  const uint32_t T = P;

  if (tid == 0) { cntG_s = 0; cntEq_s = 0; }
  __syncthreads();
#pragma unroll
  for (int k2 = 0; k2 < 16; ++k2) {
    const uint32_t key = kreg[k2];
    const int l = tid + (k2 << 8);
    if (key > T) {
      Cand[b * TOPC + atomicAdd(&cntG_s, 1)] = l;
    } else if (key == T) {
      eqIdx[atomicAdd(&cntEq_s, 1)] = l;
    }
  }
  __syncthreads();
  const int G = cntG_s;
  const int nEq = cntEq_s;
  for (int j = 0; j < need; ++j) {
    int mv2 = 0x7FFFFFFF;
    for (int i = tid; i < nEq; i += 256) mv2 = min(mv2, eqIdx[i]);
#pragma unroll
    for (int off = 32; off; off >>= 1) mv2 = min(mv2, __shfl_xor(mv2, off));
    if (lane == 0) wsum[wv] = mv2;
    __syncthreads();
    if (tid == 0) {
      int m2 = min(min(wsum[0], wsum[1]), min(wsum[2], wsum[3]));
      Cand[b * TOPC + G + j] = m2;
      minv_s = m2;
    }
    __syncthreads();
    for (int i = tid; i < nEq; i += 256)
      if (eqIdx[i] == minv_s) eqIdx[i] = 0x7FFFFFFF;
    __syncthreads();
  }
}

// ---------------------------------------------------------------------------
// Kernel 5: exact fp32 rescreen — per 256-key chunk, Mcp[b][c][u] =
// max_s dot(q_cand_u, k_s). K chunk staged in LDS (broadcast reads).
// ---------------------------------------------------------------------------
__global__ __launch_bounds__(256) void rescreen_kernel(const float* __restrict__ x,
                                                       const int* __restrict__ idx,
                                                       const int* __restrict__ Cand,
                                                       float* __restrict__ Mcp) {
  __shared__ float Kr[256][KPAD];
  __shared__ float mred[4][TOPC];
  __shared__ int cl[TOPC];
  const int c = blockIdx.x, b = blockIdx.y;
  const int tid = threadIdx.x;
  const float* xb = x + (size_t)b * LSEQ * D;
  if (tid < TOPC) cl[tid] = Cand[b * TOPC + tid];
  for (int i = tid; i < 256 * D; i += 256) {
    const int j = i / D, d = i - j * D;
    Kr[j][d] = xb[(size_t)idx[c * 256 + j] * D + d];
  }
  __syncthreads();
  const int u = tid & 63, sub = tid >> 6;
  const float* qr = xb + (size_t)cl[u] * D;
  float q[D];
#pragma unroll
  for (int d = 0; d < D; ++d) q[d] = qr[d];
  float mm = -INFINITY;
  for (int s = sub * 64; s < sub * 64 + 64; ++s) {
    float a0 = 0.f, a1 = 0.f;
#pragma unroll
    for (int d = 0; d < 44; d += 4) {
      a0 = fmaf(q[d + 0], Kr[s][d + 0], a0);
      a1 = fmaf(q[d + 1], Kr[s][d + 1], a1);
      a0 = fmaf(q[d + 2], Kr[s][d + 2], a0);
      a1 = fmaf(q[d + 3], Kr[s][d + 3], a1);
    }
    a0 = fmaf(q[44], Kr[s][44], a0);
    mm = fmaxf(mm, a0 + a1);
  }
  mred[sub][u] = mm;
  __syncthreads();
  if (tid < TOPC)
    Mcp[((size_t)b * 16 + c) * TOPC + tid] =
        fmaxf(fmaxf(mred[0][tid], mred[1][tid]), fmaxf(mred[2][tid], mred[3][tid]));
}

// ---------------------------------------------------------------------------
// Kernel 6: exact top-45 among the 64 candidates (value desc, index asc —
// jax.lax.top_k tie order) and gather Qg.
// ---------------------------------------------------------------------------
__global__ __launch_bounds__(256) void select_kernel(const float* __restrict__ x,
                                                     const float* __restrict__ Ksump,
                                                     const int* __restrict__ Cand,
                                                     const float* __restrict__ Mcp,
                                                     float* __restrict__ Qg) {
  __shared__ float ks[KPAD];
  __shared__ unsigned long long keys[TOPC];
  __shared__ int sel[U];
  const int b = blockIdx.x;
  const int tid = threadIdx.x;
  if (tid < KPAD) {
    float s = 0.f;
    if (tid < D)
      for (int cc = 0; cc < 16; ++cc) s += Ksump[((size_t)b * 16 + cc) * KPAD + tid];
    ks[tid] = s;
  }
  __syncthreads();
  if (tid < TOPC) {
    const int l = Cand[b * TOPC + tid];
    float mx = -INFINITY;
    for (int c = 0; c < 16; ++c) mx = fmaxf(mx, Mcp[((size_t)b * 16 + c) * TOPC + tid]);
    const float* xr = x + ((size_t)b * LSEQ + l) * D;
    float dot = 0.f;
    for (int d = 0; d < D; ++d) dot = fmaf(xr[d], ks[d], dot);
    const float Mv = mx - dot * (1.0f / LSEQ);
    uint32_t u = __float_as_uint(Mv);
    u ^= (u & 0x80000000u) ? 0xFFFFFFFFu : 0x80000000u;
    keys[tid] = ((unsigned long long)u << 32) | (unsigned long long)(4095 - l);
  }
  __syncthreads();
  if (tid < TOPC) {
    const unsigned long long ku = keys[tid];
    int rank = 0;
    for (int v = 0; v < TOPC; ++v) rank += (keys[v] > ku);
    if (rank < U) sel[rank] = 4095 - (int)(ku & 0xFFFFFFFFull);
  }
  __syncthreads();
  const float* xb = x + (size_t)b * LSEQ * D;
  for (int i = tid; i < U * D; i += 256) {
    const int u2 = i / D, d = i - u2 * D;
    Qg[(size_t)b * U * D + i] = xb[(size_t)sel[u2] * D + d];
  }
}

// ---------------------------------------------------------------------------
// Kernel 7: sparse attention, 64-row chunks for occupancy.
// Grid (NCH=64, NB) = 512 blocks, ~32 KB LDS (vs 93 KB / 128 blocks before).
// Lane owns row l (x-row in 45 VGPRs); wave sub covers 12 u-columns; Q read
// from LDS via wave-uniform broadcast. PV pass accumulates partial [45][46]
// (col 45 = softmax denominator).
// ---------------------------------------------------------------------------
__global__ __launch_bounds__(256) void attn_pv_kernel(const float* __restrict__ x,
                                                      const float* __restrict__ Qg,
                                                      float* __restrict__ PVpart) {
  __shared__ float Xs[CH][D + 2];  // [64][47], col 45 = 1.0; stride 47 = conflict-free
  __shared__ float eS[CH][D + 2];
  __shared__ float Qs[U * D];      // 8100 B
  const int chunk = blockIdx.x, b = blockIdx.y;
  const int tid = threadIdx.x;
  const int l0 = chunk * CH;
  const float* xb = x + ((size_t)b * LSEQ + l0) * D;
  for (int i = tid; i < CH * D; i += 256) {
    const int l = i / D, d = i - l * D;
    Xs[l][d] = xb[i];
  }
  const float* qb = Qg + (size_t)b * U * D;
  for (int i = tid; i < U * D; i += 256) Qs[i] = qb[i];
  if (tid < CH) Xs[tid][D] = 1.0f;
  __syncthreads();

  const int l = tid & 63, sub = tid >> 6;
  float xr[D];
#pragma unroll
  for (int d = 0; d < D; ++d) xr[d] = Xs[l][d];
  const float scale = 0.14907119849998599f;  // 1/sqrt(45)
  const int u0 = sub * 12;
  const int uend = (u0 + 12 < U) ? u0 + 12 : U;
  for (int u = u0; u < uend; ++u) {
    float acc = 0.f;
#pragma unroll
    for (int d = 0; d < D; ++d) acc = fmaf(Qs[u * D + d], xr[d], acc);  // uniform LDS bcast
    eS[l][u] = __expf(acc * scale);
  }
  __syncthreads();

  float* outp = PVpart + (size_t)(b * NCH + chunk) * (U * (D + 1));
  for (int idx2 = tid; idx2 < U * (D + 1); idx2 += 256) {
    const int u = idx2 / (D + 1), c = idx2 - u * (D + 1);
    float acc = 0.f;
#pragma unroll 4
    for (int ll = 0; ll < CH; ++ll) acc = fmaf(eS[ll][u], Xs[ll][c], acc);
    outp[idx2] = acc;
  }
}

// ---------------------------------------------------------------------------
// Kernel 8: combine NCH PV partials -> LN1 -> FFN -> LN2 -> out.
// ---------------------------------------------------------------------------
__global__ void epilogue_kernel(const float* __restrict__ PVpart,
                                const float* __restrict__ W1, const float* __restrict__ b1,
                                const float* __restrict__ W2, const float* __restrict__ b2,
                                const float* __restrict__ g1, const float* __restrict__ be1,
                                const float* __restrict__ g2, const float* __restrict__ be2,
                                float* __restrict__ out) {
  __shared__ float hA[D][46];
  __shared__ float den[U];
  __shared__ float Wbuf[FH * D];
  __shared__ float f1s[D][FH + 1];
  __shared__ float f2T[D][46];
  const int b = blockIdx.x;
  const int tid = threadIdx.x;
  const float* PV = PVpart + (size_t)b * NCH * U * (D + 1);
  if (tid < U) {
    float s = 0.f;
    for (int c = 0; c < NCH; ++c) s += PV[(size_t)c * U * (D + 1) + tid * (D + 1) + D];
    den[tid] = 1.0f / s;
  }
  for (int i = tid; i < FH * D; i += 256) Wbuf[i] = W1[i];
  __syncthreads();
  for (int i = tid; i < U * D; i += 256) {
    const int u = i / D, d = i - u * D;
    float s = 0.f;
    for (int c = 0; c < NCH; ++c) s += PV[(size_t)c * U * (D + 1) + u * (D + 1) + d];
    hA[u][d] = s * den[u];
  }
  __syncthreads();
  if (tid < U) {
    const int u = tid;
    float mean = 0.f;
    for (int d = 0; d < D; ++d) mean += hA[u][d];
    mean *= (1.0f / D);
    float var = 0.f;
    for (int d = 0; d < D; ++d) { float t = hA[u][d] - mean; var += t * t; }
    var *= (1.0f / D);
    const float inv = 1.0f / sqrtf(var + LN_EPS);
    for (int d = 0; d < D; ++d) hA[u][d] = g1[d] * ((hA[u][d] - mean) * inv) + be1[d];
  }
  __syncthreads();
  for (int i = tid; i < D * FH; i += 256) {
    const int d = i >> 7, hh = i & 127;
    float acc = b1[hh];
    for (int uu = 0; uu < U; ++uu) acc = fmaf(hA[uu][d], Wbuf[hh * D + uu], acc);
    f1s[d][hh] = fmaxf(acc, 0.f);
  }
  __syncthreads();
  for (int i = tid; i < U * FH; i += 256) Wbuf[i] = W2[i];
  __syncthreads();
  for (int i = tid; i < U * D; i += 256) {
    const int u = i / D, d = i - u * D;
    float acc = b2[u];
    for (int h = 0; h < FH; ++h) acc = fmaf(f1s[d][h], Wbuf[u * FH + h], acc);
    f2T[u][d] = acc;
  }
  __syncthreads();
  if (tid < U) {
    const int u = tid;
    float mean = 0.f;
    for (int d = 0; d < D; ++d) mean += f2T[u][d];
    mean *= (1.0f / D);
    float var = 0.f;
    for (int d = 0; d < D; ++d) { float t = f2T[u][d] - mean; var += t * t; }
    var *= (1.0f / D);
    const float inv = 1.0f / sqrtf(var + LN_EPS);
    float* ob = out + ((size_t)b * U + u) * D;
    for (int d = 0; d < D; ++d) ob[d] = g2[d] * ((f2T[u][d] - mean) * inv) + be2[d];
  }
}

// ---------------------------------------------------------------------------
extern "C" void kernel_launch(void* const* d_in, const int* in_sizes, int n_in,
                              void* d_out, int out_size, void* d_ws, size_t ws_size,
                              hipStream_t stream) {
  const float* x = (const float*)d_in[0];
  const float* W1 = (const float*)d_in[1];
  const float* b1 = (const float*)d_in[2];
  const float* W2 = (const float*)d_in[3];
  const float* b2 = (const float*)d_in[4];
  const float* g1 = (const float*)d_in[5];
  const float* be1 = (const float*)d_in[6];
  const float* g2 = (const float*)d_in[7];
  const float* be2 = (const float*)d_in[8];
  const int* idx = (const int*)d_in[9];
  float* out = (float*)d_out;

  // ws layout: Xh|Xl|Kh|Kl (bf16, 12.6MB) | Ksump | Mpart | Mapx | Cand |
  //            Mcp | Qg   (~15 MiB total)
  // PVpart (NB*NCH*45*46 fp32 = 4.2 MB) overlays Xh|Xl — dead after qkmax.
  const size_t NBF = (size_t)NB * LSEQ * KPAD;  // elems per bf16 buffer
  char* w = (char*)d_ws;
  ushort* Xh = (ushort*)w;
  ushort* Xl = Xh + NBF;
  ushort* Kh = Xl + NBF;
  ushort* Kl = Kh + NBF;
  float* Ksump = (float*)(Kl + NBF);
  float* Mpart = Ksump + (size_t)NB * 16 * KPAD;
  float* Mapx = Mpart + (size_t)SSPLIT * NB * LSEQ;
  int* Cand = (int*)(Mapx + (size_t)NB * LSEQ);
  float* Mcp = (float*)(Cand + NB * TOPC);
  float* Qg = Mcp + (size_t)NB * 16 * TOPC;
  float* PVpart = (float*)Xh;  // overlay (stream-ordered: attn_pv after qkmax)

  convert_kernel<<<dim3(16, NB, 2), 256, 0, stream>>>(x, idx, Xh, Xl, Kh, Kl, Ksump);
  qkmax_kernel<<<dim3(LSEQ / 256, NB, SSPLIT), 256, 0, stream>>>(Xh, Xl, Kh, Kl, Mpart);
  meanM_kernel<<<dim3(16, NB), 256, 0, stream>>>(x, Ksump, Mpart, Mapx);
  topk_kernel<<<dim3(NB), 256, 0, stream>>>(Mapx, Cand);
  rescreen_kernel<<<dim3(16, NB), 256, 0, stream>>>(x, idx, Cand, Mcp);
  select_kernel<<<dim3(NB), 256, 0, stream>>>(x, Ksump, Cand, Mcp, Qg);
  attn_pv_kernel<<<dim3(NCH, NB), 256, 0, stream>>>(x, Qg, PVpart);
  epilogue_kernel<<<dim3(NB), 256, 0, stream>>>(PVpart, W1, b1, W2, b2, g1, be1, g2, be2, out);
}

// Round 9
// 177.909 us; speedup vs baseline: 2.0012x; 1.0718x over previous
//
#include <hip/hip_runtime.h>
#include <hip/hip_bf16.h>

#define D 45
#define LSEQ 4096
#define NB 8
#define U 45
#define FH 128
#define KPAD 48        // padded row length (elems) for bf16 hi/lo buffers
#define TOPC 64        // screened candidate count (rescreened exactly)
#define SSPLIT 8       // s-range slices for qkmax
#define CH 64          // attn_pv rows per chunk
#define NCH (LSEQ / CH)  // 64 chunks
constexpr float LN_EPS = 1e-12f;

typedef __attribute__((ext_vector_type(8))) short short8v;   // 8 x bf16
typedef __attribute__((ext_vector_type(4))) float float4v;   // MFMA C/D

// ---------------------------------------------------------------------------
// Kernel 1: split-bf16 conversion.
//   z=0: Xh/Xl[b][l][0..47]  = hi/lo(x[b][l][d])  (row-major, zero-padded)
//   z=1: Kh/Kl[b][s][0..47]  = hi/lo(x[b][idx[s]][d]) + per-chunk Ksum partials
// ---------------------------------------------------------------------------
__global__ __launch_bounds__(256) void convert_kernel(const float* __restrict__ x,
                                                      const int* __restrict__ idx,
                                                      ushort* __restrict__ Xh, ushort* __restrict__ Xl,
                                                      ushort* __restrict__ Kh, ushort* __restrict__ Kl,
                                                      float* __restrict__ Ksump) {
  const int c = blockIdx.x, b = blockIdx.y, z = blockIdx.z;
  const int tid = threadIdx.x;
  const int r0 = c * 256;
  const float* xb = x + (size_t)b * LSEQ * D;
  ushort* dh = (z == 0 ? Xh : Kh) + ((size_t)b * LSEQ + r0) * KPAD;
  ushort* dl = (z == 0 ? Xl : Kl) + ((size_t)b * LSEQ + r0) * KPAD;
  for (int i = tid; i < 256 * KPAD; i += 256) {
    const int j = i / KPAD, d = i - j * KPAD;
    const int row = (z == 0) ? (r0 + j) : idx[r0 + j];
    const float v = (d < D) ? xb[(size_t)row * D + d] : 0.0f;
    __hip_bfloat16 h = __float2bfloat16(v);
    const float hf = __bfloat162float(h);
    __hip_bfloat16 lo = __float2bfloat16(v - hf);
    dh[i] = reinterpret_cast<ushort&>(h);
    dl[i] = reinterpret_cast<ushort&>(lo);
  }
  if (z == 1) {  // deterministic per-chunk Ksum partial (combined later)
    __shared__ float kp[4][KPAD];
    const int g = tid >> 6, d = tid & 63;
    float acc = 0.f;
    if (d < D)
      for (int j = g; j < 256; j += 4) acc += xb[(size_t)idx[r0 + j] * D + d];
    if (d < KPAD) kp[g][d] = (d < D) ? acc : 0.f;
    __syncthreads();
    if (tid < D)
      Ksump[((size_t)b * 16 + c) * KPAD + tid] =
          kp[0][tid] + kp[1][tid] + kp[2][tid] + kp[3][tid];
  }
}

// ---------------------------------------------------------------------------
// Kernel 2 (HOT): split-bf16 MFMA QK^T row-max, 4 l-tiles per wave.
// ---------------------------------------------------------------------------
__global__ __launch_bounds__(256) void qkmax_kernel(const ushort* __restrict__ Xh,
                                                    const ushort* __restrict__ Xl,
                                                    const ushort* __restrict__ Kh,
                                                    const ushort* __restrict__ Kl,
                                                    float* __restrict__ Mpart) {
  const int b = blockIdx.y, sc = blockIdx.z;
  const int tid = threadIdx.x, lane = tid & 63, wv = tid >> 6;
  const int l0 = blockIdx.x * 256 + wv * 64;  // wave's 64 q-rows
  const int g = lane >> 4, r16 = lane & 15;

  short8v Ah0[4], Al0[4], Ah1[4], Al1[4];
#pragma unroll
  for (int lt = 0; lt < 4; ++lt) {
    const ushort* xh = Xh + ((size_t)b * LSEQ + l0 + lt * 16 + r16) * KPAD + 8 * g;
    const ushort* xl = Xl + ((size_t)b * LSEQ + l0 + lt * 16 + r16) * KPAD + 8 * g;
    Ah0[lt] = *(const short8v*)xh;
    Al0[lt] = *(const short8v*)xl;
    Ah1[lt] = {};
    Al1[lt] = {};
    if (g < 2) { Ah1[lt] = *(const short8v*)(xh + 32); Al1[lt] = *(const short8v*)(xl + 32); }
  }

  const size_t srow0 = (size_t)b * LSEQ + sc * (LSEQ / SSPLIT) + r16;
  const ushort* khB = Kh + srow0 * KPAD + 8 * g;
  const ushort* klB = Kl + srow0 * KPAD + 8 * g;

  float mx[4][4];
#pragma unroll
  for (int lt = 0; lt < 4; ++lt)
#pragma unroll
    for (int r = 0; r < 4; ++r) mx[lt][r] = -INFINITY;

#pragma unroll 2
  for (int st = 0; st < (LSEQ / SSPLIT) / 16; ++st) {
    const ushort* kh = khB + st * (16 * KPAD);
    const ushort* kl = klB + st * (16 * KPAD);
    short8v Bh0 = *(const short8v*)kh;
    short8v Bl0 = *(const short8v*)kl;
    short8v Bh1 = {}, Bl1 = {};
    if (g < 2) { Bh1 = *(const short8v*)(kh + 32); Bl1 = *(const short8v*)(kl + 32); }
#pragma unroll
    for (int lt = 0; lt < 4; ++lt) {
      float4v acc = {0.f, 0.f, 0.f, 0.f};
      acc = __builtin_amdgcn_mfma_f32_16x16x32_bf16(Ah0[lt], Bh0, acc, 0, 0, 0);
      acc = __builtin_amdgcn_mfma_f32_16x16x32_bf16(Ah1[lt], Bh1, acc, 0, 0, 0);
      acc = __builtin_amdgcn_mfma_f32_16x16x32_bf16(Ah0[lt], Bl0, acc, 0, 0, 0);
      acc = __builtin_amdgcn_mfma_f32_16x16x32_bf16(Ah1[lt], Bl1, acc, 0, 0, 0);
      acc = __builtin_amdgcn_mfma_f32_16x16x32_bf16(Al0[lt], Bh0, acc, 0, 0, 0);
      acc = __builtin_amdgcn_mfma_f32_16x16x32_bf16(Al1[lt], Bh1, acc, 0, 0, 0);
      mx[lt][0] = fmaxf(mx[lt][0], acc[0]);
      mx[lt][1] = fmaxf(mx[lt][1], acc[1]);
      mx[lt][2] = fmaxf(mx[lt][2], acc[2]);
      mx[lt][3] = fmaxf(mx[lt][3], acc[3]);
    }
  }

#pragma unroll
  for (int lt = 0; lt < 4; ++lt)
#pragma unroll
    for (int r = 0; r < 4; ++r) {
      float v = mx[lt][r];
      v = fmaxf(v, __shfl_xor(v, 1));
      v = fmaxf(v, __shfl_xor(v, 2));
      v = fmaxf(v, __shfl_xor(v, 4));
      v = fmaxf(v, __shfl_xor(v, 8));
      if (r16 == 0)
        Mpart[((size_t)sc * NB + b) * LSEQ + l0 + lt * 16 + g * 4 + r] = v;
    }
}

// ---------------------------------------------------------------------------
// Kernel 3: Mapx[b][l] = max_sc(Mpart) - dot(x_l, Ksum)/L   (fp32 mean term)
// ---------------------------------------------------------------------------
__global__ __launch_bounds__(256) void meanM_kernel(const float* __restrict__ x,
                                                    const float* __restrict__ Ksump,
                                                    const float* __restrict__ Mpart,
                                                    float* __restrict__ Mapx) {
  __shared__ float ks[KPAD];
  const int c = blockIdx.x, b = blockIdx.y;
  const int tid = threadIdx.x;
  if (tid < KPAD) {
    float s = 0.f;
    if (tid < D)
      for (int cc = 0; cc < 16; ++cc) s += Ksump[((size_t)b * 16 + cc) * KPAD + tid];
    ks[tid] = s;
  }
  __syncthreads();
  const int l = c * 256 + tid;
  const float* xr = x + ((size_t)b * LSEQ + l) * D;
  float dot = 0.f;
  for (int d = 0; d < D; ++d) dot = fmaf(xr[d], ks[d], dot);
  float mx = Mpart[(size_t)b * LSEQ + l];
  for (int sl = 1; sl < SSPLIT; ++sl)
    mx = fmaxf(mx, Mpart[((size_t)sl * NB + b) * LSEQ + l]);
  Mapx[(size_t)b * LSEQ + l] = mx - dot * (1.0f / LSEQ);
}

// ---------------------------------------------------------------------------
// Kernel 4: radix-select the top-64 candidate SET by approximate M.
// ---------------------------------------------------------------------------
__global__ __launch_bounds__(256) void topk_kernel(const float* __restrict__ Mapx,
                                                   int* __restrict__ Cand) {
  __shared__ int hist[256];
  __shared__ int wsum[4];
  __shared__ int bin_s, need_s, cntG_s, cntEq_s, minv_s;
  __shared__ int eqIdx[LSEQ];
  const int b = blockIdx.x;
  const int tid = threadIdx.x;
  const int lane = tid & 63, wv = tid >> 6;
  uint32_t kreg[16];
#pragma unroll
  for (int k2 = 0; k2 < 16; ++k2) {
    const int l = tid + (k2 << 8);
    uint32_t u = __float_as_uint(Mapx[(size_t)b * LSEQ + l]);
    u ^= (u & 0x80000000u) ? 0xFFFFFFFFu : 0x80000000u;
    kreg[k2] = u;
  }
  const uint32_t pmaskA[4] = {0u, 0xFF000000u, 0xFFFF0000u, 0xFFFFFF00u};
  uint32_t P = 0;
  int need = TOPC;
#pragma unroll
  for (int r = 0; r < 4; ++r) {
    const int shift = 24 - 8 * r;
    hist[tid] = 0;
    __syncthreads();
#pragma unroll
    for (int k2 = 0; k2 < 16; ++k2) {
      const uint32_t key = kreg[k2];
      if (((key ^ P) & pmaskA[r]) == 0) atomicAdd(&hist[(key >> shift) & 0xFF], 1);
    }
    __syncthreads();
    const int h = hist[255 - tid];
    int s = h;
#pragma unroll
    for (int off = 1; off < 64; off <<= 1) {
      int t2 = __shfl_up(s, off);
      if (lane >= off) s += t2;
    }
    if (lane == 63) wsum[wv] = s;
    __syncthreads();
    for (int w2 = 0; w2 < wv; ++w2) s += wsum[w2];
    const int above = s - h;
    if (above < need && s >= need) { bin_s = 255 - tid; need_s = need - above; }
    __syncthreads();
    P |= ((uint32_t)bin_s) << shift;
    need = need_s;
    __syncthreads();
  }
  const uint32_t T = P;

  if (tid == 0) { cntG_s = 0; cntEq_s = 0; }
  __syncthreads();
#pragma unroll
  for (int k2 = 0; k2 < 16; ++k2) {
    const uint32_t key = kreg[k2];
    const int l = tid + (k2 << 8);
    if (key > T) {
      Cand[b * TOPC + atomicAdd(&cntG_s, 1)] = l;
    } else if (key == T) {
      eqIdx[atomicAdd(&cntEq_s, 1)] = l;
    }
  }
  __syncthreads();
  const int G = cntG_s;
  const int nEq = cntEq_s;
  for (int j = 0; j < need; ++j) {
    int mv2 = 0x7FFFFFFF;
    for (int i = tid; i < nEq; i += 256) mv2 = min(mv2, eqIdx[i]);
#pragma unroll
    for (int off = 32; off; off >>= 1) mv2 = min(mv2, __shfl_xor(mv2, off));
    if (lane == 0) wsum[wv] = mv2;
    __syncthreads();
    if (tid == 0) {
      int m2 = min(min(wsum[0], wsum[1]), min(wsum[2], wsum[3]));
      Cand[b * TOPC + G + j] = m2;
      minv_s = m2;
    }
    __syncthreads();
    for (int i = tid; i < nEq; i += 256)
      if (eqIdx[i] == minv_s) eqIdx[i] = 0x7FFFFFFF;
    __syncthreads();
  }
}

// ---------------------------------------------------------------------------
// Kernel 5: exact fp32 rescreen — per 256-key chunk, Mcp[b][c][u] =
// max_s dot(q_cand_u, k_s). K chunk staged in LDS (broadcast reads).
// ---------------------------------------------------------------------------
__global__ __launch_bounds__(256) void rescreen_kernel(const float* __restrict__ x,
                                                       const int* __restrict__ idx,
                                                       const int* __restrict__ Cand,
                                                       float* __restrict__ Mcp) {
  __shared__ float Kr[256][KPAD];
  __shared__ float mred[4][TOPC];
  __shared__ int cl[TOPC];
  const int c = blockIdx.x, b = blockIdx.y;
  const int tid = threadIdx.x;
  const float* xb = x + (size_t)b * LSEQ * D;
  if (tid < TOPC) cl[tid] = Cand[b * TOPC + tid];
  for (int i = tid; i < 256 * D; i += 256) {
    const int j = i / D, d = i - j * D;
    Kr[j][d] = xb[(size_t)idx[c * 256 + j] * D + d];
  }
  __syncthreads();
  const int u = tid & 63, sub = tid >> 6;
  const float* qr = xb + (size_t)cl[u] * D;
  float q[D];
#pragma unroll
  for (int d = 0; d < D; ++d) q[d] = qr[d];
  float mm = -INFINITY;
  for (int s = sub * 64; s < sub * 64 + 64; ++s) {
    float a0 = 0.f, a1 = 0.f;
#pragma unroll
    for (int d = 0; d < 44; d += 4) {
      a0 = fmaf(q[d + 0], Kr[s][d + 0], a0);
      a1 = fmaf(q[d + 1], Kr[s][d + 1], a1);
      a0 = fmaf(q[d + 2], Kr[s][d + 2], a0);
      a1 = fmaf(q[d + 3], Kr[s][d + 3], a1);
    }
    a0 = fmaf(q[44], Kr[s][44], a0);
    mm = fmaxf(mm, a0 + a1);
  }
  mred[sub][u] = mm;
  __syncthreads();
  if (tid < TOPC)
    Mcp[((size_t)b * 16 + c) * TOPC + tid] =
        fmaxf(fmaxf(mred[0][tid], mred[1][tid]), fmaxf(mred[2][tid], mred[3][tid]));
}

// ---------------------------------------------------------------------------
// Kernel 6: exact top-45 among the 64 candidates (value desc, index asc —
// jax.lax.top_k tie order) and gather Qg.
// ---------------------------------------------------------------------------
__global__ __launch_bounds__(256) void select_kernel(const float* __restrict__ x,
                                                     const float* __restrict__ Ksump,
                                                     const int* __restrict__ Cand,
                                                     const float* __restrict__ Mcp,
                                                     float* __restrict__ Qg) {
  __shared__ float ks[KPAD];
  __shared__ unsigned long long keys[TOPC];
  __shared__ int sel[U];
  const int b = blockIdx.x;
  const int tid = threadIdx.x;
  if (tid < KPAD) {
    float s = 0.f;
    if (tid < D)
      for (int cc = 0; cc < 16; ++cc) s += Ksump[((size_t)b * 16 + cc) * KPAD + tid];
    ks[tid] = s;
  }
  __syncthreads();
  if (tid < TOPC) {
    const int l = Cand[b * TOPC + tid];
    float mx = -INFINITY;
    for (int c = 0; c < 16; ++c) mx = fmaxf(mx, Mcp[((size_t)b * 16 + c) * TOPC + tid]);
    const float* xr = x + ((size_t)b * LSEQ + l) * D;
    float dot = 0.f;
    for (int d = 0; d < D; ++d) dot = fmaf(xr[d], ks[d], dot);
    const float Mv = mx - dot * (1.0f / LSEQ);
    uint32_t u = __float_as_uint(Mv);
    u ^= (u & 0x80000000u) ? 0xFFFFFFFFu : 0x80000000u;
    keys[tid] = ((unsigned long long)u << 32) | (unsigned long long)(4095 - l);
  }
  __syncthreads();
  if (tid < TOPC) {
    const unsigned long long ku = keys[tid];
    int rank = 0;
    for (int v = 0; v < TOPC; ++v) rank += (keys[v] > ku);
    if (rank < U) sel[rank] = 4095 - (int)(ku & 0xFFFFFFFFull);
  }
  __syncthreads();
  const float* xb = x + (size_t)b * LSEQ * D;
  for (int i = tid; i < U * D; i += 256) {
    const int u2 = i / D, d = i - u2 * D;
    Qg[(size_t)b * U * D + i] = xb[(size_t)sel[u2] * D + d];
  }
}

// ---------------------------------------------------------------------------
// Kernel 7: sparse attention, 64-row chunks for occupancy.
// ---------------------------------------------------------------------------
__global__ __launch_bounds__(256) void attn_pv_kernel(const float* __restrict__ x,
                                                      const float* __restrict__ Qg,
                                                      float* __restrict__ PVpart) {
  __shared__ float Xs[CH][D + 2];  // [64][47], col 45 = 1.0
  __shared__ float eS[CH][D + 2];
  __shared__ float Qs[U * D];      // 8100 B
  const int chunk = blockIdx.x, b = blockIdx.y;
  const int tid = threadIdx.x;
  const int l0 = chunk * CH;
  const float* xb = x + ((size_t)b * LSEQ + l0) * D;
  for (int i = tid; i < CH * D; i += 256) {
    const int l = i / D, d = i - l * D;
    Xs[l][d] = xb[i];
  }
  const float* qb = Qg + (size_t)b * U * D;
  for (int i = tid; i < U * D; i += 256) Qs[i] = qb[i];
  if (tid < CH) Xs[tid][D] = 1.0f;
  __syncthreads();

  const int l = tid & 63, sub = tid >> 6;
  float xr[D];
#pragma unroll
  for (int d = 0; d < D; ++d) xr[d] = Xs[l][d];
  const float scale = 0.14907119849998599f;  // 1/sqrt(45)
  const int u0 = sub * 12;
  const int uend = (u0 + 12 < U) ? u0 + 12 : U;
  for (int u = u0; u < uend; ++u) {
    float acc = 0.f;
#pragma unroll
    for (int d = 0; d < D; ++d) acc = fmaf(Qs[u * D + d], xr[d], acc);  // uniform LDS bcast
    eS[l][u] = __expf(acc * scale);
  }
  __syncthreads();

  float* outp = PVpart + (size_t)(b * NCH + chunk) * (U * (D + 1));
  for (int idx2 = tid; idx2 < U * (D + 1); idx2 += 256) {
    const int u = idx2 / (D + 1), c = idx2 - u * (D + 1);
    float acc = 0.f;
#pragma unroll 4
    for (int ll = 0; ll < CH; ++ll) acc = fmaf(eS[ll][u], Xs[ll][c], acc);
    outp[idx2] = acc;
  }
}

// ---------------------------------------------------------------------------
// Kernel 8: parallel combine of NCH PV partials -> hC[b][u][0..45]
// Grid (U, NB) = 360 blocks. 4 c-groups x 46 cols; LDS tree for final sum.
// ---------------------------------------------------------------------------
__global__ __launch_bounds__(256) void combine_kernel(const float* __restrict__ PVpart,
                                                      float* __restrict__ hC) {
  __shared__ float part[4][D + 1];
  const int u = blockIdx.x, b = blockIdx.y;
  const int tid = threadIdx.x;
  const int g = tid >> 6, col = tid & 63;
  if (col <= D) {
    const float* base = PVpart + ((size_t)b * NCH + g * (NCH / 4)) * (U * (D + 1)) +
                        (size_t)u * (D + 1) + col;
    float s = 0.f;
#pragma unroll 4
    for (int c = 0; c < NCH / 4; ++c) s += base[(size_t)c * (U * (D + 1))];
    part[g][col] = s;
  }
  __syncthreads();
  if (tid <= D)
    hC[((size_t)b * U + u) * (D + 1) + tid] =
        (part[0][tid] + part[1][tid]) + (part[2][tid] + part[3][tid]);
}

// ---------------------------------------------------------------------------
// Kernel 9: normalize -> LN1 -> FFN -> LN2 -> out. Reads only compact hC.
// ---------------------------------------------------------------------------
__global__ __launch_bounds__(256) void ffn_kernel(const float* __restrict__ hC,
                                                  const float* __restrict__ W1, const float* __restrict__ b1,
                                                  const float* __restrict__ W2, const float* __restrict__ b2,
                                                  const float* __restrict__ g1, const float* __restrict__ be1,
                                                  const float* __restrict__ g2, const float* __restrict__ be2,
                                                  float* __restrict__ out) {
  __shared__ float hA[D][46];
  __shared__ float den[U];
  __shared__ float Wbuf[FH * D];
  __shared__ float f1s[D][FH + 1];
  __shared__ float f2T[D][46];
  const int b = blockIdx.x;
  const int tid = threadIdx.x;
  const float* hc = hC + (size_t)b * U * (D + 1);
  if (tid < U) den[tid] = 1.0f / hc[tid * (D + 1) + D];
  for (int i = tid; i < FH * D; i += 256) Wbuf[i] = W1[i];
  __syncthreads();
  for (int i = tid; i < U * D; i += 256) {
    const int u = i / D, d = i - u * D;
    hA[u][d] = hc[u * (D + 1) + d] * den[u];
  }
  __syncthreads();
  if (tid < U) {
    const int u = tid;
    float mean = 0.f;
    for (int d = 0; d < D; ++d) mean += hA[u][d];
    mean *= (1.0f / D);
    float var = 0.f;
    for (int d = 0; d < D; ++d) { float t = hA[u][d] - mean; var += t * t; }
    var *= (1.0f / D);
    const float inv = 1.0f / sqrtf(var + LN_EPS);
    for (int d = 0; d < D; ++d) hA[u][d] = g1[d] * ((hA[u][d] - mean) * inv) + be1[d];
  }
  __syncthreads();
  for (int i = tid; i < D * FH; i += 256) {
    const int d = i >> 7, hh = i & 127;
    float acc = b1[hh];
    for (int uu = 0; uu < U; ++uu) acc = fmaf(hA[uu][d], Wbuf[hh * D + uu], acc);
    f1s[d][hh] = fmaxf(acc, 0.f);
  }
  __syncthreads();
  for (int i = tid; i < U * FH; i += 256) Wbuf[i] = W2[i];
  __syncthreads();
  for (int i = tid; i < U * D; i += 256) {
    const int u = i / D, d = i - u * D;
    float acc = b2[u];
    for (int h = 0; h < FH; ++h) acc = fmaf(f1s[d][h], Wbuf[u * FH + h], acc);
    f2T[u][d] = acc;
  }
  __syncthreads();
  if (tid < U) {
    const int u = tid;
    float mean = 0.f;
    for (int d = 0; d < D; ++d) mean += f2T[u][d];
    mean *= (1.0f / D);
    float var = 0.f;
    for (int d = 0; d < D; ++d) { float t = f2T[u][d] - mean; var += t * t; }
    var *= (1.0f / D);
    const float inv = 1.0f / sqrtf(var + LN_EPS);
    float* ob = out + ((size_t)b * U + u) * D;
    for (int d = 0; d < D; ++d) ob[d] = g2[d] * ((f2T[u][d] - mean) * inv) + be2[d];
  }
}

// ---------------------------------------------------------------------------
extern "C" void kernel_launch(void* const* d_in, const int* in_sizes, int n_in,
                              void* d_out, int out_size, void* d_ws, size_t ws_size,
                              hipStream_t stream) {
  const float* x = (const float*)d_in[0];
  const float* W1 = (const float*)d_in[1];
  const float* b1 = (const float*)d_in[2];
  const float* W2 = (const float*)d_in[3];
  const float* b2 = (const float*)d_in[4];
  const float* g1 = (const float*)d_in[5];
  const float* be1 = (const float*)d_in[6];
  const float* g2 = (const float*)d_in[7];
  const float* be2 = (const float*)d_in[8];
  const int* idx = (const int*)d_in[9];
  float* out = (float*)d_out;

  // ws layout: Xh|Xl|Kh|Kl (bf16, 12.6MB) | Ksump | Mpart | Mapx | Cand |
  //            Mcp | Qg | hC   (~15 MiB total)
  // PVpart (NB*NCH*45*46 fp32 = 4.2 MB) overlays Xh|Xl — dead after qkmax.
  const size_t NBF = (size_t)NB * LSEQ * KPAD;  // elems per bf16 buffer
  char* w = (char*)d_ws;
  ushort* Xh = (ushort*)w;
  ushort* Xl = Xh + NBF;
  ushort* Kh = Xl + NBF;
  ushort* Kl = Kh + NBF;
  float* Ksump = (float*)(Kl + NBF);
  float* Mpart = Ksump + (size_t)NB * 16 * KPAD;
  float* Mapx = Mpart + (size_t)SSPLIT * NB * LSEQ;
  int* Cand = (int*)(Mapx + (size_t)NB * LSEQ);
  float* Mcp = (float*)(Cand + NB * TOPC);
  float* Qg = Mcp + (size_t)NB * 16 * TOPC;
  float* hC = Qg + (size_t)NB * U * D;
  float* PVpart = (float*)Xh;  // overlay (stream-ordered: attn_pv after qkmax)

  convert_kernel<<<dim3(16, NB, 2), 256, 0, stream>>>(x, idx, Xh, Xl, Kh, Kl, Ksump);
  qkmax_kernel<<<dim3(LSEQ / 256, NB, SSPLIT), 256, 0, stream>>>(Xh, Xl, Kh, Kl, Mpart);
  meanM_kernel<<<dim3(16, NB), 256, 0, stream>>>(x, Ksump, Mpart, Mapx);
  topk_kernel<<<dim3(NB), 256, 0, stream>>>(Mapx, Cand);
  rescreen_kernel<<<dim3(16, NB), 256, 0, stream>>>(x, idx, Cand, Mcp);
  select_kernel<<<dim3(NB), 256, 0, stream>>>(x, Ksump, Cand, Mcp, Qg);
  attn_pv_kernel<<<dim3(NCH, NB), 256, 0, stream>>>(x, Qg, PVpart);
  combine_kernel<<<dim3(U, NB), 256, 0, stream>>>(PVpart, hC);
  ffn_kernel<<<dim3(NB), 256, 0, stream>>>(hC, W1, b1, W2, b2, g1, be1, g2, be2, out);
}